// Round 1
// baseline (14795.728 us; speedup 1.0000x reference)
//
#include <hip/hip_runtime.h>
#include <hip/hip_cooperative_groups.h>
#include <cmath>

namespace cg = cooperative_groups;

// Problem constants (match reference)
constexpr int   B        = 4;
constexpr int   P        = 2048;   // P1 == P2
constexpr int   D        = 64;
constexpr float EPS      = 0.1f;
constexpr float THRESH   = 0.1f;
constexpr int   MAX_ITER = 100;

constexpr float LOG2E   = 1.44269504088896340736f;
constexpr float LN2     = 0.69314718055994530942f;
constexpr float SCALE   = LOG2E / EPS;   // natural -> log2 domain, /eps folded in
constexpr float UNSCALE = EPS * LN2;     // inverse

// ws layout (floats): u2s[8192] | v2s[8192] | uo[8192] | err[128]   (~99 KB, proven OK)
constexpr int WS_U   = 0;
constexpr int WS_V   = 8192;
constexpr int WS_UO  = 16384;
constexpr int WS_ERR = 24576;
constexpr int WS_FLOATS = 24704;

__device__ __forceinline__ float max4(float4 a) {
    return fmaxf(fmaxf(a.x, a.y), fmaxf(a.z, a.w));
}

// ============ prep: C = sum_d (x-y)^2, register-tiled; zero scratch ============
__global__ __launch_bounds__(256)
void prep_kernel(const float* __restrict__ x, const float* __restrict__ y,
                 float* __restrict__ out, float* __restrict__ ws)
{
    const int bid = blockIdx.x, tid = threadIdx.x;
    const int bb = bid >> 9, tr = (bid >> 4) & 31, tc = bid & 15;
    const int row0 = tr * 64, col0 = tc * 128;

    if (bid == 0) {
        for (int i = tid; i < WS_FLOATS; i += 256) ws[i] = 0.0f;
        if (tid < B) out[tid] = 0.0f;
    }

    __shared__ float xs[64 * 65];
    __shared__ float ys[128 * 65];
    for (int i = tid; i < 64 * 64; i += 256) {
        int r = i >> 6, d = i & 63;
        xs[r * 65 + d] = x[(size_t)(bb * P + row0 + r) * D + d];
    }
    for (int i = tid; i < 128 * 64; i += 256) {
        int c = i >> 6, d = i & 63;
        ys[c * 65 + d] = y[(size_t)(bb * P + col0 + c) * D + d];
    }
    __syncthreads();

    const int tx = tid & 15, ty = tid >> 4;
    float acc[4][8];
    #pragma unroll
    for (int j = 0; j < 4; ++j)
        #pragma unroll
        for (int i = 0; i < 8; ++i) acc[j][i] = 0.0f;

    #pragma unroll 4
    for (int k = 0; k < 64; ++k) {
        float xa[4], yb[8];
        #pragma unroll
        for (int j = 0; j < 4; ++j) xa[j] = xs[(ty * 4 + j) * 65 + k];
        #pragma unroll
        for (int i = 0; i < 8; ++i) yb[i] = ys[(tx * 8 + i) * 65 + k];
        #pragma unroll
        for (int j = 0; j < 4; ++j)
            #pragma unroll
            for (int i = 0; i < 8; ++i) {
                float d = xa[j] - yb[i];
                acc[j][i] = fmaf(d, d, acc[j][i]);
            }
    }

    float* C_out = out + B + (size_t)B * P * P;
    #pragma unroll
    for (int j = 0; j < 4; ++j) {
        size_t base = (size_t)(bb * P + row0 + ty * 4 + j) * P + col0 + tx * 8;
        float4 a0 = make_float4(acc[j][0], acc[j][1], acc[j][2], acc[j][3]);
        float4 a1 = make_float4(acc[j][4], acc[j][5], acc[j][6], acc[j][7]);
        ((float4*)&C_out[base])[0] = a0;
        ((float4*)&C_out[base])[1] = a1;
    }
}

// ============ persistent cooperative kernel: C in registers for ALL iterations ============
// grid 512 = B*128, 2 blocks/CU co-resident (64 KB LDS each). Block owns 16 rows
// x 2048 cols of pre-scaled C in registers (c2[4][8] per thread, loaded ONCE).
// Per iteration: u-update (row-local, registers) -> v block-partials -> LDS merge
// -> global partials -> grid.sync -> distributed combine -> grid.sync -> err check.
// Epilogue (pi, cost) fused, reusing register-resident C.
__global__ __launch_bounds__(256, 2)
void persist_kernel(const float* C, float* part_m, float* part_s,
                    float* ws, float* out)
{
    cg::grid_group grid = cg::this_grid();
    float* v2s = ws + WS_V;
    float* err = ws + WS_ERR;

    const int bid = blockIdx.x, tid = threadIdx.x;
    const int w = tid >> 6, l = tid & 63;
    const int bb = bid >> 7, rc = bid & 127;
    const int row0 = rc * 16;
    const int baserow = bb * P + row0 + w * 4;

    __shared__ float4 m_lds[4 * 512];                  // 32 KB
    __shared__ float4 s_lds[4 * 512];                  // 32 KB

    const float A = EPS * __logf(1.0f / (float)P + 1e-8f);

    // ---- load C tile ONCE, pre-scaled: c2 = -C/eps*log2e ----
    float4 c2[4][8];
    #pragma unroll
    for (int j = 0; j < 4; ++j) {
        const float4* Crow = (const float4*)(C + (size_t)(baserow + j) * P);
        #pragma unroll
        for (int k = 0; k < 8; ++k) {
            float4 cc = Crow[l + 64 * k];
            c2[j][k] = make_float4(-SCALE * cc.x, -SCALE * cc.y,
                                   -SCALE * cc.z, -SCALE * cc.w);
        }
    }
    // Opaque identity: forbid the compiler from re-materializing these as
    // global loads inside the iteration loop (they must stay in VGPRs).
    #pragma unroll
    for (int j = 0; j < 4; ++j)
        #pragma unroll
        for (int k = 0; k < 8; ++k)
            asm volatile("" : "+v"(c2[j][k].x), "+v"(c2[j][k].y),
                              "+v"(c2[j][k].z), "+v"(c2[j][k].w));

    float u_old[4] = {0.0f, 0.0f, 0.0f, 0.0f};         // natural-log u, wave-uniform
    float u2row[4] = {0.0f, 0.0f, 0.0f, 0.0f};

    for (int t = 0; t < MAX_ITER; ++t) {
        // v (pre-scaled) for this lane's 32 columns — fresh from last combine
        const float4* vv = (const float4*)(v2s + bb * P);
        float4 v4[8];
        #pragma unroll
        for (int k = 0; k < 8; ++k) v4[k] = vv[l + 64 * k];

        // ---- u update per row (exact max-then-sum LSE) ----
        float dsum = 0.0f;
        #pragma unroll
        for (int j = 0; j < 4; ++j) {
            float m = -1e30f;
            #pragma unroll
            for (int k = 0; k < 8; ++k) {
                float4 tt = make_float4(v4[k].x + c2[j][k].x, v4[k].y + c2[j][k].y,
                                        v4[k].z + c2[j][k].z, v4[k].w + c2[j][k].w);
                m = fmaxf(m, max4(tt));
            }
            #pragma unroll
            for (int off = 1; off < 64; off <<= 1) m = fmaxf(m, __shfl_xor(m, off));
            float s = 0.0f;
            #pragma unroll
            for (int k = 0; k < 8; ++k) {
                s += exp2f(v4[k].x + c2[j][k].x - m) + exp2f(v4[k].y + c2[j][k].y - m)
                   + exp2f(v4[k].z + c2[j][k].z - m) + exp2f(v4[k].w + c2[j][k].w - m);
            }
            #pragma unroll
            for (int off = 1; off < 64; off <<= 1) s += __shfl_xor(s, off);
            float u_nat = A - UNSCALE * (m + log2f(s));
            u2row[j] = u_nat * SCALE;
            dsum += fabsf(u_nat - u_old[j]);           // wave-uniform
            u_old[j] = u_nat;
        }
        if (l == 0) atomicAdd(&err[t], dsum);          // one per wave

        // ---- v partials over this wave's 4 rows (fresh u) ----
        #pragma unroll
        for (int k = 0; k < 8; ++k) {
            float4 t0 = make_float4(u2row[0] + c2[0][k].x, u2row[0] + c2[0][k].y,
                                    u2row[0] + c2[0][k].z, u2row[0] + c2[0][k].w);
            float4 t1 = make_float4(u2row[1] + c2[1][k].x, u2row[1] + c2[1][k].y,
                                    u2row[1] + c2[1][k].z, u2row[1] + c2[1][k].w);
            float4 t2 = make_float4(u2row[2] + c2[2][k].x, u2row[2] + c2[2][k].y,
                                    u2row[2] + c2[2][k].z, u2row[2] + c2[2][k].w);
            float4 t3 = make_float4(u2row[3] + c2[3][k].x, u2row[3] + c2[3][k].y,
                                    u2row[3] + c2[3][k].z, u2row[3] + c2[3][k].w);
            float4 pm, ps;
            pm.x = fmaxf(fmaxf(t0.x, t1.x), fmaxf(t2.x, t3.x));
            pm.y = fmaxf(fmaxf(t0.y, t1.y), fmaxf(t2.y, t3.y));
            pm.z = fmaxf(fmaxf(t0.z, t1.z), fmaxf(t2.z, t3.z));
            pm.w = fmaxf(fmaxf(t0.w, t1.w), fmaxf(t2.w, t3.w));
            ps.x = exp2f(t0.x - pm.x) + exp2f(t1.x - pm.x) + exp2f(t2.x - pm.x) + exp2f(t3.x - pm.x);
            ps.y = exp2f(t0.y - pm.y) + exp2f(t1.y - pm.y) + exp2f(t2.y - pm.y) + exp2f(t3.y - pm.y);
            ps.z = exp2f(t0.z - pm.z) + exp2f(t1.z - pm.z) + exp2f(t2.z - pm.z) + exp2f(t3.z - pm.z);
            ps.w = exp2f(t0.w - pm.w) + exp2f(t1.w - pm.w) + exp2f(t2.w - pm.w) + exp2f(t3.w - pm.w);
            m_lds[w * 512 + l + 64 * k] = pm;
            s_lds[w * 512 + l + 64 * k] = ps;
        }
        __syncthreads();

        // ---- cross-wave merge -> block partial (2048 cols) ----
        float4* pm_out = ((float4*)part_m) + (size_t)bid * 512;
        float4* ps_out = ((float4*)part_s) + (size_t)bid * 512;
        #pragma unroll
        for (int h = 0; h < 2; ++h) {
            const int idx = tid * 2 + h;               // float4 column index 0..511
            float4 M = m_lds[idx], S = s_lds[idx];
            #pragma unroll
            for (int q = 1; q < 4; ++q) {
                float4 pm = m_lds[q * 512 + idx], ps = s_lds[q * 512 + idx];
                float m2;
                m2 = fmaxf(M.x, pm.x); S.x = S.x * exp2f(M.x - m2) + ps.x * exp2f(pm.x - m2); M.x = m2;
                m2 = fmaxf(M.y, pm.y); S.y = S.y * exp2f(M.y - m2) + ps.y * exp2f(pm.y - m2); M.y = m2;
                m2 = fmaxf(M.z, pm.z); S.z = S.z * exp2f(M.z - m2) + ps.z * exp2f(pm.z - m2); M.z = m2;
                m2 = fmaxf(M.w, pm.w); S.w = S.w * exp2f(M.w - m2) + ps.w * exp2f(pm.w - m2); M.w = m2;
            }
            pm_out[idx] = M;
            ps_out[idx] = S;
        }

        grid.sync();                                   // partials visible everywhere

        // ---- distributed combine: every block folds 16 columns, 16 lanes/col ----
        {
            const int ci  = tid >> 4;                  // column within block's group
            const int sub = tid & 15;                  // chunk sub-group
            const int g   = bid * 16 + ci;             // global column 0..8191
            const int b2  = g >> 11, c = g & (P - 1);
            const float* pmb = part_m + (size_t)(b2 * 128 + sub * 8) * P + c;
            const float* psb = part_s + (size_t)(b2 * 128 + sub * 8) * P + c;
            float M = -1e30f, S = 0.0f;
            #pragma unroll
            for (int q = 0; q < 8; ++q) {
                float pm = pmb[(size_t)q * P];
                float ps = psb[(size_t)q * P];
                float m2 = fmaxf(M, pm);
                S = S * exp2f(M - m2) + ps * exp2f(pm - m2);
                M = m2;
            }
            #pragma unroll
            for (int off = 1; off < 16; off <<= 1) {   // merge across the 16-lane group
                float pm = __shfl_xor(M, off);
                float ps = __shfl_xor(S, off);
                float m2 = fmaxf(M, pm);
                S = S * exp2f(M - m2) + ps * exp2f(pm - m2);
                M = m2;
            }
            if (sub == 0)
                v2s[g] = (A - UNSCALE * (M + log2f(S))) * SCALE;
        }

        grid.sync();                                   // v visible everywhere

        if (err[t] < 4.0f * THRESH) break;             // uniform device-side break
    }

    // ---- fused epilogue: pi = exp((u+v-C)/eps), cost = sum pi*C ----
    {
        const float4* vv = (const float4*)(v2s + bb * P);
        float4 v4[8];
        #pragma unroll
        for (int k = 0; k < 8; ++k) v4[k] = vv[l + 64 * k];

        float* cost = out;
        float* pi   = out + B;
        float lc = 0.0f;
        #pragma unroll
        for (int j = 0; j < 4; ++j) {
            const int r = row0 + w * 4 + j;
            float4* Prow = (float4*)(pi + (size_t)(bb * P + r) * P);
            const float u2 = u2row[j];
            #pragma unroll
            for (int k = 0; k < 8; ++k) {
                float4 p, cc;
                cc.x = -UNSCALE * c2[j][k].x;          // recover C from register copy
                cc.y = -UNSCALE * c2[j][k].y;
                cc.z = -UNSCALE * c2[j][k].z;
                cc.w = -UNSCALE * c2[j][k].w;
                p.x = exp2f(u2 + v4[k].x + c2[j][k].x);
                p.y = exp2f(u2 + v4[k].y + c2[j][k].y);
                p.z = exp2f(u2 + v4[k].z + c2[j][k].z);
                p.w = exp2f(u2 + v4[k].w + c2[j][k].w);
                lc = fmaf(p.x, cc.x, lc); lc = fmaf(p.y, cc.y, lc);
                lc = fmaf(p.z, cc.z, lc); lc = fmaf(p.w, cc.w, lc);
                Prow[l + 64 * k] = p;
            }
        }
        #pragma unroll
        for (int off = 1; off < 64; off <<= 1) lc += __shfl_xor(lc, off);
        __syncthreads();                               // LDS now free for reuse
        float* sm = (float*)m_lds;
        if (l == 0) sm[w] = lc;
        __syncthreads();
        if (tid == 0) atomicAdd(&cost[bb], sm[0] + sm[1] + sm[2] + sm[3]);
    }
}

// ============ fallback path (previous proven kernels) ============
__global__ __launch_bounds__(256, 2)
void iter_kernel(const float* __restrict__ C, float* __restrict__ part_m,
                 float* __restrict__ part_s, float* __restrict__ ws, int t)
{
    float* u2s = ws + WS_U;
    float* v2s = ws + WS_V;
    float* uo  = ws + WS_UO;
    float* err = ws + WS_ERR;
    if (t > 0 && err[t - 1] < 4.0f * THRESH) return;

    const int bid = blockIdx.x, tid = threadIdx.x;
    const int w = tid >> 6, l = tid & 63;
    const int bb = bid >> 7, rc = bid & 127;
    const int row0 = rc * 16;
    const int baserow = bb * P + row0 + w * 4;

    __shared__ float4 m_lds[4 * 512];
    __shared__ float4 s_lds[4 * 512];

    const float A = EPS * __logf(1.0f / (float)P + 1e-8f);

    const float4* vv = (const float4*)(v2s + bb * P);
    float4 v4[8];
    #pragma unroll
    for (int k = 0; k < 8; ++k) v4[k] = vv[l + 64 * k];

    float4 c2[4][8];
    #pragma unroll
    for (int j = 0; j < 4; ++j) {
        const float4* Crow = (const float4*)(C + (size_t)(baserow + j) * P);
        #pragma unroll
        for (int k = 0; k < 8; ++k) {
            float4 cc = Crow[l + 64 * k];
            c2[j][k] = make_float4(-SCALE * cc.x, -SCALE * cc.y,
                                   -SCALE * cc.z, -SCALE * cc.w);
        }
    }

    float u2row[4];
    float dsum = 0.0f;
    #pragma unroll
    for (int j = 0; j < 4; ++j) {
        float m = -1e30f;
        #pragma unroll
        for (int k = 0; k < 8; ++k) {
            float4 tt = make_float4(v4[k].x + c2[j][k].x, v4[k].y + c2[j][k].y,
                                    v4[k].z + c2[j][k].z, v4[k].w + c2[j][k].w);
            m = fmaxf(m, max4(tt));
        }
        #pragma unroll
        for (int off = 1; off < 64; off <<= 1) m = fmaxf(m, __shfl_xor(m, off));
        float s = 0.0f;
        #pragma unroll
        for (int k = 0; k < 8; ++k) {
            s += exp2f(v4[k].x + c2[j][k].x - m) + exp2f(v4[k].y + c2[j][k].y - m)
               + exp2f(v4[k].z + c2[j][k].z - m) + exp2f(v4[k].w + c2[j][k].w - m);
        }
        #pragma unroll
        for (int off = 1; off < 64; off <<= 1) s += __shfl_xor(s, off);
        float u_nat = A - UNSCALE * (m + log2f(s));
        u2row[j] = u_nat * SCALE;
        if (l == 0) {
            const int rg = baserow + j;
            dsum += fabsf(u_nat - uo[rg]);
            uo[rg]  = u_nat;
            u2s[rg] = u2row[j];
        }
    }
    if (l == 0) atomicAdd(&err[t], dsum);

    #pragma unroll
    for (int k = 0; k < 8; ++k) {
        float4 t0 = make_float4(u2row[0] + c2[0][k].x, u2row[0] + c2[0][k].y,
                                u2row[0] + c2[0][k].z, u2row[0] + c2[0][k].w);
        float4 t1 = make_float4(u2row[1] + c2[1][k].x, u2row[1] + c2[1][k].y,
                                u2row[1] + c2[1][k].z, u2row[1] + c2[1][k].w);
        float4 t2 = make_float4(u2row[2] + c2[2][k].x, u2row[2] + c2[2][k].y,
                                u2row[2] + c2[2][k].z, u2row[2] + c2[2][k].w);
        float4 t3 = make_float4(u2row[3] + c2[3][k].x, u2row[3] + c2[3][k].y,
                                u2row[3] + c2[3][k].z, u2row[3] + c2[3][k].w);
        float4 pm, ps;
        pm.x = fmaxf(fmaxf(t0.x, t1.x), fmaxf(t2.x, t3.x));
        pm.y = fmaxf(fmaxf(t0.y, t1.y), fmaxf(t2.y, t3.y));
        pm.z = fmaxf(fmaxf(t0.z, t1.z), fmaxf(t2.z, t3.z));
        pm.w = fmaxf(fmaxf(t0.w, t1.w), fmaxf(t2.w, t3.w));
        ps.x = exp2f(t0.x - pm.x) + exp2f(t1.x - pm.x) + exp2f(t2.x - pm.x) + exp2f(t3.x - pm.x);
        ps.y = exp2f(t0.y - pm.y) + exp2f(t1.y - pm.y) + exp2f(t2.y - pm.y) + exp2f(t3.y - pm.y);
        ps.z = exp2f(t0.z - pm.z) + exp2f(t1.z - pm.z) + exp2f(t2.z - pm.z) + exp2f(t3.z - pm.z);
        ps.w = exp2f(t0.w - pm.w) + exp2f(t1.w - pm.w) + exp2f(t2.w - pm.w) + exp2f(t3.w - pm.w);
        m_lds[w * 512 + l + 64 * k] = pm;
        s_lds[w * 512 + l + 64 * k] = ps;
    }
    __syncthreads();

    float4* pm_out = ((float4*)part_m) + (size_t)bid * 512;
    float4* ps_out = ((float4*)part_s) + (size_t)bid * 512;
    #pragma unroll
    for (int h = 0; h < 2; ++h) {
        const int idx = tid * 2 + h;
        float4 M = m_lds[idx], S = s_lds[idx];
        #pragma unroll
        for (int q = 1; q < 4; ++q) {
            float4 pm = m_lds[q * 512 + idx], ps = s_lds[q * 512 + idx];
            float m2;
            m2 = fmaxf(M.x, pm.x); S.x = S.x * exp2f(M.x - m2) + ps.x * exp2f(pm.x - m2); M.x = m2;
            m2 = fmaxf(M.y, pm.y); S.y = S.y * exp2f(M.y - m2) + ps.y * exp2f(pm.y - m2); M.y = m2;
            m2 = fmaxf(M.z, pm.z); S.z = S.z * exp2f(M.z - m2) + ps.z * exp2f(pm.z - m2); M.z = m2;
            m2 = fmaxf(M.w, pm.w); S.w = S.w * exp2f(M.w - m2) + ps.w * exp2f(pm.w - m2); M.w = m2;
        }
        pm_out[idx] = M;
        ps_out[idx] = S;
    }
}

__global__ __launch_bounds__(256)
void comb_kernel(const float* __restrict__ part_m, const float* __restrict__ part_s,
                 float* __restrict__ ws, int t)
{
    float* v2s = ws + WS_V;
    float* err = ws + WS_ERR;
    if (t > 0 && err[t - 1] < 4.0f * THRESH) return;

    const int g = blockIdx.x * 256 + threadIdx.x;
    const int b = g >> 11, c = g & (P - 1);
    const float* pmb = part_m + (size_t)(b * 128) * P + c;
    const float* psb = part_s + (size_t)(b * 128) * P + c;

    const float A = EPS * __logf(1.0f / (float)P + 1e-8f);

    float M = -1e30f;
    #pragma unroll 8
    for (int q = 0; q < 128; ++q) M = fmaxf(M, pmb[(size_t)q * P]);
    float S = 0.0f;
    #pragma unroll 8
    for (int q = 0; q < 128; ++q)
        S = fmaf(psb[(size_t)q * P], exp2f(pmb[(size_t)q * P] - M), S);

    float v_nat = A - UNSCALE * (M + log2f(S));
    v2s[g] = v_nat * SCALE;
}

__global__ __launch_bounds__(256)
void epi_kernel(float* __restrict__ out, const float* __restrict__ ws)
{
    const float* u2s = ws + WS_U;
    const float* v2s = ws + WS_V;
    float* cost = out;
    float* pi   = out + B;
    const float* C = out + B + (size_t)B * P * P;

    const int bid = blockIdx.x, tid = threadIdx.x;
    const int w = tid >> 6, l = tid & 63;
    const int bb = bid >> 7, rc = bid & 127;
    const int row0 = rc * 16;

    const float4* vv = (const float4*)(v2s + bb * P);
    float4 v4[8];
    #pragma unroll
    for (int k = 0; k < 8; ++k) v4[k] = vv[l + 64 * k];

    float lc = 0.0f;
    #pragma unroll
    for (int j = 0; j < 4; ++j) {
        const int r = row0 + w * 4 + j;
        const float u2 = u2s[bb * P + r];
        const float4* Crow = (const float4*)(C  + (size_t)(bb * P + r) * P);
        float4*       Prow = (float4*)      (pi + (size_t)(bb * P + r) * P);
        #pragma unroll
        for (int k = 0; k < 8; ++k) {
            float4 cc = Crow[l + 64 * k];
            float4 p;
            p.x = exp2f(u2 + v4[k].x - SCALE * cc.x);
            p.y = exp2f(u2 + v4[k].y - SCALE * cc.y);
            p.z = exp2f(u2 + v4[k].z - SCALE * cc.z);
            p.w = exp2f(u2 + v4[k].w - SCALE * cc.w);
            lc = fmaf(p.x, cc.x, lc); lc = fmaf(p.y, cc.y, lc);
            lc = fmaf(p.z, cc.z, lc); lc = fmaf(p.w, cc.w, lc);
            Prow[l + 64 * k] = p;
        }
    }
    #pragma unroll
    for (int off = 1; off < 64; off <<= 1) lc += __shfl_xor(lc, off);
    __shared__ float sm[4];
    if (l == 0) sm[w] = lc;
    __syncthreads();
    if (tid == 0) atomicAdd(&cost[bb], sm[0] + sm[1] + sm[2] + sm[3]);
}

extern "C" void kernel_launch(void* const* d_in, const int* in_sizes, int n_in,
                              void* d_out, int out_size, void* d_ws, size_t ws_size,
                              hipStream_t stream) {
    const float* x = (const float*)d_in[0];
    const float* y = (const float*)d_in[1];
    float* out = (float*)d_out;
    float* ws  = (float*)d_ws;
    const float* C = out + B + (size_t)B * P * P;
    // chunk partials live in the pi region (overwritten by epilogue): 2 x 4 MB
    float* part_m = out + B;
    float* part_s = part_m + 512 * P;

    prep_kernel<<<2048, 256, 0, stream>>>(x, y, out, ws);

    void* args[] = { (void*)&C, (void*)&part_m, (void*)&part_s,
                     (void*)&ws, (void*)&out };
    hipError_t e = hipLaunchCooperativeKernel((void*)persist_kernel,
                                              dim3(512), dim3(256),
                                              args, 0, stream);
    if (e != hipSuccess) {
        // fallback: previous proven multi-kernel path
        for (int t = 0; t < MAX_ITER; ++t) {
            iter_kernel<<<512, 256, 0, stream>>>(C, part_m, part_s, ws, t);
            comb_kernel<<<32,  256, 0, stream>>>(part_m, part_s, ws, t);
        }
        epi_kernel<<<512, 256, 0, stream>>>(out, ws);
    }
}

// Round 2
// 14721.468 us; speedup vs baseline: 1.0050x; 1.0050x over previous
//
#include <hip/hip_runtime.h>
#include <cmath>

// Problem constants (match reference)
constexpr int   B        = 4;
constexpr int   P        = 2048;   // P1 == P2
constexpr int   D        = 64;
constexpr float EPS      = 0.1f;
constexpr float THRESH   = 0.1f;
constexpr int   MAX_ITER = 100;

constexpr float LOG2E   = 1.44269504088896340736f;
constexpr float LN2     = 0.69314718055994530942f;
constexpr float SCALE   = LOG2E / EPS;   // natural -> log2 domain, /eps folded in
constexpr float UNSCALE = EPS * LN2;     // inverse

// ws layout (floats): u2s[8192] | v2s[8192] | uo[8192] | err[128] | bar[2]
constexpr int WS_U   = 0;
constexpr int WS_V   = 8192;
constexpr int WS_UO  = 16384;
constexpr int WS_ERR = 24576;
constexpr int WS_BAR = 24704;
constexpr int WS_FLOATS = 24712;

constexpr int NBLK = 1024;   // persistent grid
constexpr int NTHR = 128;

__device__ __forceinline__ float max4(float4 a) {
    return fmaxf(fmaxf(a.x, a.y), fmaxf(a.z, a.w));
}

// ---- system-scope (cross-XCD coherent, L2-bypassing) access helpers ----
__device__ __forceinline__ float ld_sys_f(const float* p) {
    return __hip_atomic_load((float*)p, __ATOMIC_RELAXED, __HIP_MEMORY_SCOPE_SYSTEM);
}
__device__ __forceinline__ void st_sys_f(float* p, float v) {
    __hip_atomic_store(p, v, __ATOMIC_RELAXED, __HIP_MEMORY_SCOPE_SYSTEM);
}
__device__ __forceinline__ unsigned long long ld_sys_u64(const void* p) {
    return __hip_atomic_load((unsigned long long*)p, __ATOMIC_RELAXED, __HIP_MEMORY_SCOPE_SYSTEM);
}
__device__ __forceinline__ float2 ld_sys_f2(const float2* p) {
    union { float2 f; unsigned long long u; } pk;
    pk.u = __hip_atomic_load((unsigned long long*)p, __ATOMIC_RELAXED, __HIP_MEMORY_SCOPE_SYSTEM);
    return pk.f;
}
__device__ __forceinline__ void st_sys_f2(float2* p, float m, float s) {
    union { float2 f; unsigned long long u; } pk;
    pk.f.x = m; pk.f.y = s;
    __hip_atomic_store((unsigned long long*)p, pk.u, __ATOMIC_RELAXED, __HIP_MEMORY_SCOPE_SYSTEM);
}

// ---- lightweight grid barrier: NO cache maintenance, monotonic counter ----
// Correct because ALL cross-block data moves via sc0sc1 (system-scope) ops:
// writers drain vmcnt before arriving; readers' system-scope loads read the
// coherence point directly, so no L2 writeback/invalidate is needed.
__device__ __forceinline__ void gbar(unsigned* cnt, unsigned target) {
    asm volatile("s_waitcnt vmcnt(0)" ::: "memory");   // every wave drains its stores
    __syncthreads();
    if (threadIdx.x == 0) {
        __hip_atomic_fetch_add(cnt, 1u, __ATOMIC_RELAXED, __HIP_MEMORY_SCOPE_SYSTEM);
        while (__hip_atomic_load(cnt, __ATOMIC_RELAXED, __HIP_MEMORY_SCOPE_SYSTEM) < target)
            __builtin_amdgcn_s_sleep(8);
    }
    __syncthreads();
}

__device__ __forceinline__ void lse_merge(float ma, float sa, float mb, float sb,
                                          float& M, float& S) {
    float m2 = fmaxf(ma, mb);
    S = sa * exp2f(ma - m2) + sb * exp2f(mb - m2);
    M = m2;
}

// ============ prep: C = sum_d (x-y)^2, register-tiled; zero scratch ============
__global__ __launch_bounds__(256)
void prep_kernel(const float* __restrict__ x, const float* __restrict__ y,
                 float* __restrict__ out, float* __restrict__ ws)
{
    const int bid = blockIdx.x, tid = threadIdx.x;
    const int bb = bid >> 9, tr = (bid >> 4) & 31, tc = bid & 15;
    const int row0 = tr * 64, col0 = tc * 128;

    if (bid == 0) {
        for (int i = tid; i < WS_FLOATS; i += 256) ws[i] = 0.0f;
        if (tid < B) out[tid] = 0.0f;
    }

    __shared__ float xs[64 * 65];
    __shared__ float ys[128 * 65];
    for (int i = tid; i < 64 * 64; i += 256) {
        int r = i >> 6, d = i & 63;
        xs[r * 65 + d] = x[(size_t)(bb * P + row0 + r) * D + d];
    }
    for (int i = tid; i < 128 * 64; i += 256) {
        int c = i >> 6, d = i & 63;
        ys[c * 65 + d] = y[(size_t)(bb * P + col0 + c) * D + d];
    }
    __syncthreads();

    const int tx = tid & 15, ty = tid >> 4;
    float acc[4][8];
    #pragma unroll
    for (int j = 0; j < 4; ++j)
        #pragma unroll
        for (int i = 0; i < 8; ++i) acc[j][i] = 0.0f;

    #pragma unroll 4
    for (int k = 0; k < 64; ++k) {
        float xa[4], yb[8];
        #pragma unroll
        for (int j = 0; j < 4; ++j) xa[j] = xs[(ty * 4 + j) * 65 + k];
        #pragma unroll
        for (int i = 0; i < 8; ++i) yb[i] = ys[(tx * 8 + i) * 65 + k];
        #pragma unroll
        for (int j = 0; j < 4; ++j)
            #pragma unroll
            for (int i = 0; i < 8; ++i) {
                float d = xa[j] - yb[i];
                acc[j][i] = fmaf(d, d, acc[j][i]);
            }
    }

    float* C_out = out + B + (size_t)B * P * P;
    #pragma unroll
    for (int j = 0; j < 4; ++j) {
        size_t base = (size_t)(bb * P + row0 + ty * 4 + j) * P + col0 + tx * 8;
        float4 a0 = make_float4(acc[j][0], acc[j][1], acc[j][2], acc[j][3]);
        float4 a1 = make_float4(acc[j][4], acc[j][5], acc[j][6], acc[j][7]);
        ((float4*)&C_out[base])[0] = a0;
        ((float4*)&C_out[base])[1] = a1;
    }
}

// ============ persistent kernel v2: register-resident C, fence-free barriers ============
// 1024 blocks x 128 threads (8 rows/block, 2 waves x 4 rows). 4 blocks/CU.
// c2[4][8] (128 VGPR) truly register-resident: no cg call boundary, <=256 VGPR cap.
// Cross-block traffic (v, partials, err) via system-scope sc0sc1 ops only, so the
// grid barrier needs no L2 writeback/invalidate.
__global__ __launch_bounds__(NTHR, 2)
void persist_kernel(const float* C, float2* part2, float* ws, float* out)
{
    float* v2s = ws + WS_V;
    float* err = ws + WS_ERR;
    unsigned* bar = (unsigned*)(ws + WS_BAR);

    const int bid = blockIdx.x, tid = threadIdx.x;
    const int w = tid >> 6, l = tid & 63;
    const int bb = bid >> 8, rc = bid & 255;
    const int row0 = rc * 8;
    const int baserow = bb * P + row0 + w * 4;

    // merge buffer: [m/s][wave][float4-col]  (32 KB). v staging aliases the front.
    __shared__ float4 mrg[2][2][512];
    float* v_lds = (float*)&mrg[0][0][0];              // 8 KB

    const float A = EPS * __logf(1.0f / (float)P + 1e-8f);

    // ---- load C tile ONCE, pre-scaled: c2 = -C/eps*log2e ----
    float4 c2[4][8];
    #pragma unroll
    for (int j = 0; j < 4; ++j) {
        const float4* Crow = (const float4*)(C + (size_t)(baserow + j) * P);
        #pragma unroll
        for (int k = 0; k < 8; ++k) {
            float4 cc = Crow[l + 64 * k];
            c2[j][k] = make_float4(-SCALE * cc.x, -SCALE * cc.y,
                                   -SCALE * cc.z, -SCALE * cc.w);
        }
    }
    #pragma unroll
    for (int j = 0; j < 4; ++j)
        #pragma unroll
        for (int k = 0; k < 8; ++k)
            asm volatile("" : "+v"(c2[j][k].x), "+v"(c2[j][k].y),
                              "+v"(c2[j][k].z), "+v"(c2[j][k].w));

    float u_old[4] = {0.0f, 0.0f, 0.0f, 0.0f};
    float u2row[4] = {0.0f, 0.0f, 0.0f, 0.0f};
    float4 v4[8];
    unsigned ep = 0;

    for (int t = 0; t < MAX_ITER; ++t) {
        // ---- stage v into LDS (coalesced system-scope loads), then to regs ----
        {
            unsigned long long* vl = (unsigned long long*)v_lds;
            const unsigned long long* vg = (const unsigned long long*)(v2s + bb * P);
            #pragma unroll
            for (int i = 0; i < 8; ++i)
                vl[tid + 128 * i] = ld_sys_u64(&vg[tid + 128 * i]);
        }
        __syncthreads();
        #pragma unroll
        for (int k = 0; k < 8; ++k) v4[k] = ((const float4*)v_lds)[l + 64 * k];
        __syncthreads();                               // before mrg overwrites staging

        // ---- u update per row (exact max-then-sum LSE, all-register) ----
        float dsum = 0.0f;
        #pragma unroll
        for (int j = 0; j < 4; ++j) {
            float m = -1e30f;
            #pragma unroll
            for (int k = 0; k < 8; ++k) {
                float4 tt = make_float4(v4[k].x + c2[j][k].x, v4[k].y + c2[j][k].y,
                                        v4[k].z + c2[j][k].z, v4[k].w + c2[j][k].w);
                m = fmaxf(m, max4(tt));
            }
            #pragma unroll
            for (int off = 1; off < 64; off <<= 1) m = fmaxf(m, __shfl_xor(m, off));
            float s = 0.0f;
            #pragma unroll
            for (int k = 0; k < 8; ++k) {
                s += exp2f(v4[k].x + c2[j][k].x - m) + exp2f(v4[k].y + c2[j][k].y - m)
                   + exp2f(v4[k].z + c2[j][k].z - m) + exp2f(v4[k].w + c2[j][k].w - m);
            }
            #pragma unroll
            for (int off = 1; off < 64; off <<= 1) s += __shfl_xor(s, off);
            float u_nat = A - UNSCALE * (m + log2f(s));
            u2row[j] = u_nat * SCALE;
            dsum += fabsf(u_nat - u_old[j]);
            u_old[j] = u_nat;
        }
        if (l == 0) atomicAdd(&err[t], dsum);          // device-scope RMW: cross-XCD ok

        // ---- v partials over this wave's 4 rows -> LDS ----
        #pragma unroll
        for (int k = 0; k < 8; ++k) {
            float4 t0 = make_float4(u2row[0] + c2[0][k].x, u2row[0] + c2[0][k].y,
                                    u2row[0] + c2[0][k].z, u2row[0] + c2[0][k].w);
            float4 t1 = make_float4(u2row[1] + c2[1][k].x, u2row[1] + c2[1][k].y,
                                    u2row[1] + c2[1][k].z, u2row[1] + c2[1][k].w);
            float4 t2 = make_float4(u2row[2] + c2[2][k].x, u2row[2] + c2[2][k].y,
                                    u2row[2] + c2[2][k].z, u2row[2] + c2[2][k].w);
            float4 t3 = make_float4(u2row[3] + c2[3][k].x, u2row[3] + c2[3][k].y,
                                    u2row[3] + c2[3][k].z, u2row[3] + c2[3][k].w);
            float4 pm, ps;
            pm.x = fmaxf(fmaxf(t0.x, t1.x), fmaxf(t2.x, t3.x));
            pm.y = fmaxf(fmaxf(t0.y, t1.y), fmaxf(t2.y, t3.y));
            pm.z = fmaxf(fmaxf(t0.z, t1.z), fmaxf(t2.z, t3.z));
            pm.w = fmaxf(fmaxf(t0.w, t1.w), fmaxf(t2.w, t3.w));
            ps.x = exp2f(t0.x - pm.x) + exp2f(t1.x - pm.x) + exp2f(t2.x - pm.x) + exp2f(t3.x - pm.x);
            ps.y = exp2f(t0.y - pm.y) + exp2f(t1.y - pm.y) + exp2f(t2.y - pm.y) + exp2f(t3.y - pm.y);
            ps.z = exp2f(t0.z - pm.z) + exp2f(t1.z - pm.z) + exp2f(t2.z - pm.z) + exp2f(t3.z - pm.z);
            ps.w = exp2f(t0.w - pm.w) + exp2f(t1.w - pm.w) + exp2f(t2.w - pm.w) + exp2f(t3.w - pm.w);
            mrg[0][w][l + 64 * k] = pm;
            mrg[1][w][l + 64 * k] = ps;
        }
        __syncthreads();

        // ---- merge 2 waves -> block partial [chunk][col] float2 (coalesced) ----
        {
            float2* pout = part2 + (size_t)(bb * 256 + rc) * 2048;
            #pragma unroll
            for (int i = 0; i < 4; ++i) {
                const int c4 = tid + 128 * i;          // dense LDS read, dense global write
                float4 ma = mrg[0][0][c4], mb = mrg[0][1][c4];
                float4 sa = mrg[1][0][c4], sb = mrg[1][1][c4];
                float M0, S0, M1, S1, M2, S2, M3, S3;
                lse_merge(ma.x, sa.x, mb.x, sb.x, M0, S0);
                lse_merge(ma.y, sa.y, mb.y, sb.y, M1, S1);
                lse_merge(ma.z, sa.z, mb.z, sb.z, M2, S2);
                lse_merge(ma.w, sa.w, mb.w, sb.w, M3, S3);
                st_sys_f2(&pout[4 * c4 + 0], M0, S0);
                st_sys_f2(&pout[4 * c4 + 1], M1, S1);
                st_sys_f2(&pout[4 * c4 + 2], M2, S2);
                st_sys_f2(&pout[4 * c4 + 3], M3, S3);
            }
        }

        gbar(bar, NBLK * (++ep));                      // partials visible

        // ---- distributed combine: 8 cols/block, 16 lanes/col x 16 chunks ----
        {
            const int ci  = tid >> 4;                  // 0..7
            const int sub = tid & 15;
            const int g   = bid * 8 + ci;              // 0..8191
            const int b2  = g >> 11, c = g & (P - 1);
            const float2* pb = part2 + (size_t)b2 * 256 * 2048 + c;
            float M = -1e30f, S = 0.0f;
            #pragma unroll
            for (int q = 0; q < 16; ++q) {
                const int ch = sub * 16 + q;
                float2 pk = ld_sys_f2(pb + (size_t)ch * 2048);
                float m2 = fmaxf(M, pk.x);
                S = S * exp2f(M - m2) + pk.y * exp2f(pk.x - m2);
                M = m2;
            }
            #pragma unroll
            for (int off = 1; off < 16; off <<= 1) {
                float pm = __shfl_xor(M, off);
                float ps = __shfl_xor(S, off);
                float m2 = fmaxf(M, pm);
                S = S * exp2f(M - m2) + ps * exp2f(pm - m2);
                M = m2;
            }
            if (sub == 0)
                st_sys_f(&v2s[g], (A - UNSCALE * (M + log2f(S))) * SCALE);
        }

        gbar(bar, NBLK * (++ep));                      // v visible

        if (ld_sys_f(&err[t]) < 4.0f * THRESH) break;  // uniform device-side break
    }

    // ---- fused epilogue: pi = exp((u+v-C)/eps), cost = sum pi*C ----
    {
        {
            unsigned long long* vl = (unsigned long long*)v_lds;
            const unsigned long long* vg = (const unsigned long long*)(v2s + bb * P);
            #pragma unroll
            for (int i = 0; i < 8; ++i)
                vl[tid + 128 * i] = ld_sys_u64(&vg[tid + 128 * i]);
        }
        __syncthreads();
        #pragma unroll
        for (int k = 0; k < 8; ++k) v4[k] = ((const float4*)v_lds)[l + 64 * k];

        float* cost = out;
        float* pi   = out + B;
        float lc = 0.0f;
        #pragma unroll
        for (int j = 0; j < 4; ++j) {
            const int r = row0 + w * 4 + j;
            float4* Prow = (float4*)(pi + (size_t)(bb * P + r) * P);
            const float u2 = u2row[j];
            #pragma unroll
            for (int k = 0; k < 8; ++k) {
                float4 p, cc;
                cc.x = -UNSCALE * c2[j][k].x;          // recover C from register copy
                cc.y = -UNSCALE * c2[j][k].y;
                cc.z = -UNSCALE * c2[j][k].z;
                cc.w = -UNSCALE * c2[j][k].w;
                p.x = exp2f(u2 + v4[k].x + c2[j][k].x);
                p.y = exp2f(u2 + v4[k].y + c2[j][k].y);
                p.z = exp2f(u2 + v4[k].z + c2[j][k].z);
                p.w = exp2f(u2 + v4[k].w + c2[j][k].w);
                lc = fmaf(p.x, cc.x, lc); lc = fmaf(p.y, cc.y, lc);
                lc = fmaf(p.z, cc.z, lc); lc = fmaf(p.w, cc.w, lc);
                Prow[l + 64 * k] = p;
            }
        }
        #pragma unroll
        for (int off = 1; off < 64; off <<= 1) lc += __shfl_xor(lc, off);
        __syncthreads();
        float* sm = v_lds;                             // reuse LDS for 2-wave reduce
        if (l == 0) sm[w] = lc;
        __syncthreads();
        if (tid == 0) atomicAdd(&cost[bb], sm[0] + sm[1]);
    }
}

// ============ fallback path (proven multi-kernel, 7704 us) ============
__global__ __launch_bounds__(256, 2)
void iter_kernel(const float* __restrict__ C, float* __restrict__ part_m,
                 float* __restrict__ part_s, float* __restrict__ ws, int t)
{
    float* u2s = ws + WS_U;
    float* v2s = ws + WS_V;
    float* uo  = ws + WS_UO;
    float* err = ws + WS_ERR;
    if (t > 0 && err[t - 1] < 4.0f * THRESH) return;

    const int bid = blockIdx.x, tid = threadIdx.x;
    const int w = tid >> 6, l = tid & 63;
    const int bb = bid >> 7, rc = bid & 127;
    const int row0 = rc * 16;
    const int baserow = bb * P + row0 + w * 4;

    __shared__ float4 m_lds[4 * 512];
    __shared__ float4 s_lds[4 * 512];

    const float A = EPS * __logf(1.0f / (float)P + 1e-8f);

    const float4* vv = (const float4*)(v2s + bb * P);
    float4 v4[8];
    #pragma unroll
    for (int k = 0; k < 8; ++k) v4[k] = vv[l + 64 * k];

    float4 c2[4][8];
    #pragma unroll
    for (int j = 0; j < 4; ++j) {
        const float4* Crow = (const float4*)(C + (size_t)(baserow + j) * P);
        #pragma unroll
        for (int k = 0; k < 8; ++k) {
            float4 cc = Crow[l + 64 * k];
            c2[j][k] = make_float4(-SCALE * cc.x, -SCALE * cc.y,
                                   -SCALE * cc.z, -SCALE * cc.w);
        }
    }

    float u2row[4];
    float dsum = 0.0f;
    #pragma unroll
    for (int j = 0; j < 4; ++j) {
        float m = -1e30f;
        #pragma unroll
        for (int k = 0; k < 8; ++k) {
            float4 tt = make_float4(v4[k].x + c2[j][k].x, v4[k].y + c2[j][k].y,
                                    v4[k].z + c2[j][k].z, v4[k].w + c2[j][k].w);
            m = fmaxf(m, max4(tt));
        }
        #pragma unroll
        for (int off = 1; off < 64; off <<= 1) m = fmaxf(m, __shfl_xor(m, off));
        float s = 0.0f;
        #pragma unroll
        for (int k = 0; k < 8; ++k) {
            s += exp2f(v4[k].x + c2[j][k].x - m) + exp2f(v4[k].y + c2[j][k].y - m)
               + exp2f(v4[k].z + c2[j][k].z - m) + exp2f(v4[k].w + c2[j][k].w - m);
        }
        #pragma unroll
        for (int off = 1; off < 64; off <<= 1) s += __shfl_xor(s, off);
        float u_nat = A - UNSCALE * (m + log2f(s));
        u2row[j] = u_nat * SCALE;
        if (l == 0) {
            const int rg = baserow + j;
            dsum += fabsf(u_nat - uo[rg]);
            uo[rg]  = u_nat;
            u2s[rg] = u2row[j];
        }
    }
    if (l == 0) atomicAdd(&err[t], dsum);

    #pragma unroll
    for (int k = 0; k < 8; ++k) {
        float4 t0 = make_float4(u2row[0] + c2[0][k].x, u2row[0] + c2[0][k].y,
                                u2row[0] + c2[0][k].z, u2row[0] + c2[0][k].w);
        float4 t1 = make_float4(u2row[1] + c2[1][k].x, u2row[1] + c2[1][k].y,
                                u2row[1] + c2[1][k].z, u2row[1] + c2[1][k].w);
        float4 t2 = make_float4(u2row[2] + c2[2][k].x, u2row[2] + c2[2][k].y,
                                u2row[2] + c2[2][k].z, u2row[2] + c2[2][k].w);
        float4 t3 = make_float4(u2row[3] + c2[3][k].x, u2row[3] + c2[3][k].y,
                                u2row[3] + c2[3][k].z, u2row[3] + c2[3][k].w);
        float4 pm, ps;
        pm.x = fmaxf(fmaxf(t0.x, t1.x), fmaxf(t2.x, t3.x));
        pm.y = fmaxf(fmaxf(t0.y, t1.y), fmaxf(t2.y, t3.y));
        pm.z = fmaxf(fmaxf(t0.z, t1.z), fmaxf(t2.z, t3.z));
        pm.w = fmaxf(fmaxf(t0.w, t1.w), fmaxf(t2.w, t3.w));
        ps.x = exp2f(t0.x - pm.x) + exp2f(t1.x - pm.x) + exp2f(t2.x - pm.x) + exp2f(t3.x - pm.x);
        ps.y = exp2f(t0.y - pm.y) + exp2f(t1.y - pm.y) + exp2f(t2.y - pm.y) + exp2f(t3.y - pm.y);
        ps.z = exp2f(t0.z - pm.z) + exp2f(t1.z - pm.z) + exp2f(t2.z - pm.z) + exp2f(t3.z - pm.z);
        ps.w = exp2f(t0.w - pm.w) + exp2f(t1.w - pm.w) + exp2f(t2.w - pm.w) + exp2f(t3.w - pm.w);
        m_lds[w * 512 + l + 64 * k] = pm;
        s_lds[w * 512 + l + 64 * k] = ps;
    }
    __syncthreads();

    float4* pm_out = ((float4*)part_m) + (size_t)bid * 512;
    float4* ps_out = ((float4*)part_s) + (size_t)bid * 512;
    #pragma unroll
    for (int h = 0; h < 2; ++h) {
        const int idx = tid * 2 + h;
        float4 M = m_lds[idx], S = s_lds[idx];
        #pragma unroll
        for (int q = 1; q < 4; ++q) {
            float4 pm = m_lds[q * 512 + idx], ps = s_lds[q * 512 + idx];
            float m2;
            m2 = fmaxf(M.x, pm.x); S.x = S.x * exp2f(M.x - m2) + ps.x * exp2f(pm.x - m2); M.x = m2;
            m2 = fmaxf(M.y, pm.y); S.y = S.y * exp2f(M.y - m2) + ps.y * exp2f(pm.y - m2); M.y = m2;
            m2 = fmaxf(M.z, pm.z); S.z = S.z * exp2f(M.z - m2) + ps.z * exp2f(pm.z - m2); M.z = m2;
            m2 = fmaxf(M.w, pm.w); S.w = S.w * exp2f(M.w - m2) + ps.w * exp2f(pm.w - m2); M.w = m2;
        }
        pm_out[idx] = M;
        ps_out[idx] = S;
    }
}

__global__ __launch_bounds__(256)
void comb_kernel(const float* __restrict__ part_m, const float* __restrict__ part_s,
                 float* __restrict__ ws, int t)
{
    float* v2s = ws + WS_V;
    float* err = ws + WS_ERR;
    if (t > 0 && err[t - 1] < 4.0f * THRESH) return;

    const int g = blockIdx.x * 256 + threadIdx.x;
    const int b = g >> 11, c = g & (P - 1);
    const float* pmb = part_m + (size_t)(b * 128) * P + c;
    const float* psb = part_s + (size_t)(b * 128) * P + c;

    const float A = EPS * __logf(1.0f / (float)P + 1e-8f);

    float M = -1e30f;
    #pragma unroll 8
    for (int q = 0; q < 128; ++q) M = fmaxf(M, pmb[(size_t)q * P]);
    float S = 0.0f;
    #pragma unroll 8
    for (int q = 0; q < 128; ++q)
        S = fmaf(psb[(size_t)q * P], exp2f(pmb[(size_t)q * P] - M), S);

    float v_nat = A - UNSCALE * (M + log2f(S));
    v2s[g] = v_nat * SCALE;
}

__global__ __launch_bounds__(256)
void epi_kernel(float* __restrict__ out, const float* __restrict__ ws)
{
    const float* u2s = ws + WS_U;
    const float* v2s = ws + WS_V;
    float* cost = out;
    float* pi   = out + B;
    const float* C = out + B + (size_t)B * P * P;

    const int bid = blockIdx.x, tid = threadIdx.x;
    const int w = tid >> 6, l = tid & 63;
    const int bb = bid >> 7, rc = bid & 127;
    const int row0 = rc * 16;

    const float4* vv = (const float4*)(v2s + bb * P);
    float4 v4[8];
    #pragma unroll
    for (int k = 0; k < 8; ++k) v4[k] = vv[l + 64 * k];

    float lc = 0.0f;
    #pragma unroll
    for (int j = 0; j < 4; ++j) {
        const int r = row0 + w * 4 + j;
        const float u2 = u2s[bb * P + r];
        const float4* Crow = (const float4*)(C  + (size_t)(bb * P + r) * P);
        float4*       Prow = (float4*)      (pi + (size_t)(bb * P + r) * P);
        #pragma unroll
        for (int k = 0; k < 8; ++k) {
            float4 cc = Crow[l + 64 * k];
            float4 p;
            p.x = exp2f(u2 + v4[k].x - SCALE * cc.x);
            p.y = exp2f(u2 + v4[k].y - SCALE * cc.y);
            p.z = exp2f(u2 + v4[k].z - SCALE * cc.z);
            p.w = exp2f(u2 + v4[k].w - SCALE * cc.w);
            lc = fmaf(p.x, cc.x, lc); lc = fmaf(p.y, cc.y, lc);
            lc = fmaf(p.z, cc.z, lc); lc = fmaf(p.w, cc.w, lc);
            Prow[l + 64 * k] = p;
        }
    }
    #pragma unroll
    for (int off = 1; off < 64; off <<= 1) lc += __shfl_xor(lc, off);
    __shared__ float sm[4];
    if (l == 0) sm[w] = lc;
    __syncthreads();
    if (tid == 0) atomicAdd(&cost[bb], sm[0] + sm[1] + sm[2] + sm[3]);
}

extern "C" void kernel_launch(void* const* d_in, const int* in_sizes, int n_in,
                              void* d_out, int out_size, void* d_ws, size_t ws_size,
                              hipStream_t stream) {
    const float* x = (const float*)d_in[0];
    const float* y = (const float*)d_in[1];
    float* out = (float*)d_out;
    float* ws  = (float*)d_ws;
    const float* C = out + B + (size_t)B * P * P;
    // persist partials: [batch][chunk 256][col 2048] float2 = 16 MB, inside pi region
    float2* part2 = (float2*)(out + B);
    // fallback partials (same region, old layout)
    float* part_m = out + B;
    float* part_s = part_m + 512 * P;

    prep_kernel<<<2048, 256, 0, stream>>>(x, y, out, ws);

    void* args[] = { (void*)&C, (void*)&part2, (void*)&ws, (void*)&out };
    hipError_t e = hipLaunchCooperativeKernel((void*)persist_kernel,
                                              dim3(NBLK), dim3(NTHR),
                                              args, 0, stream);
    if (e != hipSuccess) {
        for (int t = 0; t < MAX_ITER; ++t) {
            iter_kernel<<<512, 256, 0, stream>>>(C, part_m, part_s, ws, t);
            comb_kernel<<<32,  256, 0, stream>>>(part_m, part_s, ws, t);
        }
        epi_kernel<<<512, 256, 0, stream>>>(out, ws);
    }
}

// Round 3
// 14430.495 us; speedup vs baseline: 1.0253x; 1.0202x over previous
//
#include <hip/hip_runtime.h>
#include <cmath>

// Problem constants (match reference)
constexpr int   B        = 4;
constexpr int   P        = 2048;   // P1 == P2
constexpr int   D        = 64;
constexpr float EPS      = 0.1f;
constexpr float THRESH   = 0.1f;
constexpr int   MAX_ITER = 100;

constexpr float LOG2E   = 1.44269504088896340736f;
constexpr float LN2     = 0.69314718055994530942f;
constexpr float SCALE   = LOG2E / EPS;   // natural -> log2 domain, /eps folded in
constexpr float UNSCALE = EPS * LN2;     // inverse

// ws layout (floats): u2s[8192] | v2s[8192] | uo[8192] | err[128] | bar[2]
constexpr int WS_U   = 0;
constexpr int WS_V   = 8192;
constexpr int WS_UO  = 16384;
constexpr int WS_ERR = 24576;
constexpr int WS_BAR = 24704;
constexpr int WS_FLOATS = 24712;

constexpr int NBLK = 1024;   // persistent grid (exactly 4 blocks/CU x 256 CU)
constexpr int NTHR = 128;

__device__ __forceinline__ float max4(float4 a) {
    return fmaxf(fmaxf(a.x, a.y), fmaxf(a.z, a.w));
}

// ---- system-scope (cross-XCD coherent, L2-bypassing) access helpers ----
__device__ __forceinline__ float ld_sys_f(const float* p) {
    return __hip_atomic_load((float*)p, __ATOMIC_RELAXED, __HIP_MEMORY_SCOPE_SYSTEM);
}
__device__ __forceinline__ void st_sys_f(float* p, float v) {
    __hip_atomic_store(p, v, __ATOMIC_RELAXED, __HIP_MEMORY_SCOPE_SYSTEM);
}
__device__ __forceinline__ unsigned long long ld_sys_u64(const void* p) {
    return __hip_atomic_load((unsigned long long*)p, __ATOMIC_RELAXED, __HIP_MEMORY_SCOPE_SYSTEM);
}
__device__ __forceinline__ float2 ld_sys_f2(const float2* p) {
    union { float2 f; unsigned long long u; } pk;
    pk.u = __hip_atomic_load((unsigned long long*)p, __ATOMIC_RELAXED, __HIP_MEMORY_SCOPE_SYSTEM);
    return pk.f;
}
__device__ __forceinline__ void st_sys_f2(float2* p, float m, float s) {
    union { float2 f; unsigned long long u; } pk;
    pk.f.x = m; pk.f.y = s;
    __hip_atomic_store((unsigned long long*)p, pk.u, __ATOMIC_RELAXED, __HIP_MEMORY_SCOPE_SYSTEM);
}

// ---- lightweight grid barrier: NO cache maintenance, monotonic counter ----
// Correct because ALL cross-block data moves via sc0sc1 (system-scope) ops:
// writers drain vmcnt before arriving; readers' system-scope loads read the
// coherence point directly, so no L2 writeback/invalidate is needed.
__device__ __forceinline__ void gbar(unsigned* cnt, unsigned target) {
    asm volatile("s_waitcnt vmcnt(0)" ::: "memory");   // every wave drains its stores
    __syncthreads();
    if (threadIdx.x == 0) {
        __hip_atomic_fetch_add(cnt, 1u, __ATOMIC_RELAXED, __HIP_MEMORY_SCOPE_SYSTEM);
        while (__hip_atomic_load(cnt, __ATOMIC_RELAXED, __HIP_MEMORY_SCOPE_SYSTEM) < target)
            __builtin_amdgcn_s_sleep(8);
    }
    __syncthreads();
}

__device__ __forceinline__ void lse_merge(float ma, float sa, float mb, float sb,
                                          float& M, float& S) {
    float m2 = fmaxf(ma, mb);
    S = sa * exp2f(ma - m2) + sb * exp2f(mb - m2);
    M = m2;
}

// ============ prep: C = sum_d (x-y)^2, register-tiled; zero scratch ============
__global__ __launch_bounds__(256)
void prep_kernel(const float* __restrict__ x, const float* __restrict__ y,
                 float* __restrict__ out, float* __restrict__ ws)
{
    const int bid = blockIdx.x, tid = threadIdx.x;
    const int bb = bid >> 9, tr = (bid >> 4) & 31, tc = bid & 15;
    const int row0 = tr * 64, col0 = tc * 128;

    if (bid == 0) {
        for (int i = tid; i < WS_FLOATS; i += 256) ws[i] = 0.0f;
        if (tid < B) out[tid] = 0.0f;
    }

    __shared__ float xs[64 * 65];
    __shared__ float ys[128 * 65];
    for (int i = tid; i < 64 * 64; i += 256) {
        int r = i >> 6, d = i & 63;
        xs[r * 65 + d] = x[(size_t)(bb * P + row0 + r) * D + d];
    }
    for (int i = tid; i < 128 * 64; i += 256) {
        int c = i >> 6, d = i & 63;
        ys[c * 65 + d] = y[(size_t)(bb * P + col0 + c) * D + d];
    }
    __syncthreads();

    const int tx = tid & 15, ty = tid >> 4;
    float acc[4][8];
    #pragma unroll
    for (int j = 0; j < 4; ++j)
        #pragma unroll
        for (int i = 0; i < 8; ++i) acc[j][i] = 0.0f;

    #pragma unroll 4
    for (int k = 0; k < 64; ++k) {
        float xa[4], yb[8];
        #pragma unroll
        for (int j = 0; j < 4; ++j) xa[j] = xs[(ty * 4 + j) * 65 + k];
        #pragma unroll
        for (int i = 0; i < 8; ++i) yb[i] = ys[(tx * 8 + i) * 65 + k];
        #pragma unroll
        for (int j = 0; j < 4; ++j)
            #pragma unroll
            for (int i = 0; i < 8; ++i) {
                float d = xa[j] - yb[i];
                acc[j][i] = fmaf(d, d, acc[j][i]);
            }
    }

    float* C_out = out + B + (size_t)B * P * P;
    #pragma unroll
    for (int j = 0; j < 4; ++j) {
        size_t base = (size_t)(bb * P + row0 + ty * 4 + j) * P + col0 + tx * 8;
        float4 a0 = make_float4(acc[j][0], acc[j][1], acc[j][2], acc[j][3]);
        float4 a1 = make_float4(acc[j][4], acc[j][5], acc[j][6], acc[j][7]);
        ((float4*)&C_out[base])[0] = a0;
        ((float4*)&C_out[base])[1] = a1;
    }
}

// ============ persistent kernel v3: register-resident C, pinned occupancy ============
// 1024 blocks x 128 threads (8 rows/block, 2 waves x 4 rows), 4 blocks/CU.
// amdgpu_waves_per_eu(2,2) pins the occupancy target: the allocator budgets 256
// VGPRs and has NO incentive to spill c2[4][8] (128 VGPR) for extra occupancy —
// this was round-2's failure (VGPR_Count=128, ~5 GB scratch thrash).
// Cross-block traffic (v, partials, err) via system-scope sc0sc1 ops only, so the
// grid barrier needs no L2 writeback/invalidate.
__global__ __attribute__((amdgpu_flat_work_group_size(NTHR, NTHR),
                          amdgpu_waves_per_eu(2, 2)))
void persist_kernel(const float* C, float2* part2, float* ws, float* out)
{
    float* v2s = ws + WS_V;
    float* err = ws + WS_ERR;
    unsigned* bar = (unsigned*)(ws + WS_BAR);

    const int bid = blockIdx.x, tid = threadIdx.x;
    const int w = tid >> 6, l = tid & 63;
    const int bb = bid >> 8, rc = bid & 255;
    const int row0 = rc * 8;
    const int baserow = bb * P + row0 + w * 4;

    // merge buffer: [m/s][wave][float4-col]  (32 KB). v staging aliases the front.
    __shared__ float4 mrg[2][2][512];
    float* v_lds = (float*)&mrg[0][0][0];              // 8 KB

    const float A = EPS * __logf(1.0f / (float)P + 1e-8f);

    // ---- load C tile ONCE, pre-scaled: c2 = -C/eps*log2e ----
    float4 c2[4][8];
    #pragma unroll
    for (int j = 0; j < 4; ++j) {
        const float4* Crow = (const float4*)(C + (size_t)(baserow + j) * P);
        #pragma unroll
        for (int k = 0; k < 8; ++k) {
            float4 cc = Crow[l + 64 * k];
            c2[j][k] = make_float4(-SCALE * cc.x, -SCALE * cc.y,
                                   -SCALE * cc.z, -SCALE * cc.w);
        }
    }
    #pragma unroll
    for (int j = 0; j < 4; ++j)
        #pragma unroll
        for (int k = 0; k < 8; ++k)
            asm volatile("" : "+v"(c2[j][k].x), "+v"(c2[j][k].y),
                              "+v"(c2[j][k].z), "+v"(c2[j][k].w));

    float u_old[4] = {0.0f, 0.0f, 0.0f, 0.0f};
    float u2row[4] = {0.0f, 0.0f, 0.0f, 0.0f};
    float4 v4[8];
    unsigned ep = 0;

    for (int t = 0; t < MAX_ITER; ++t) {
        // ---- stage v into LDS (coalesced system-scope loads), then to regs ----
        {
            unsigned long long* vl = (unsigned long long*)v_lds;
            const unsigned long long* vg = (const unsigned long long*)(v2s + bb * P);
            #pragma unroll
            for (int i = 0; i < 8; ++i)
                vl[tid + 128 * i] = ld_sys_u64(&vg[tid + 128 * i]);
        }
        __syncthreads();
        #pragma unroll
        for (int k = 0; k < 8; ++k) v4[k] = ((const float4*)v_lds)[l + 64 * k];
        __syncthreads();                               // before mrg overwrites staging

        // ---- u update per row (exact max-then-sum LSE, all-register) ----
        float dsum = 0.0f;
        #pragma unroll
        for (int j = 0; j < 4; ++j) {
            float m = -1e30f;
            #pragma unroll
            for (int k = 0; k < 8; ++k) {
                float4 tt = make_float4(v4[k].x + c2[j][k].x, v4[k].y + c2[j][k].y,
                                        v4[k].z + c2[j][k].z, v4[k].w + c2[j][k].w);
                m = fmaxf(m, max4(tt));
            }
            #pragma unroll
            for (int off = 1; off < 64; off <<= 1) m = fmaxf(m, __shfl_xor(m, off));
            float s = 0.0f;
            #pragma unroll
            for (int k = 0; k < 8; ++k) {
                s += exp2f(v4[k].x + c2[j][k].x - m) + exp2f(v4[k].y + c2[j][k].y - m)
                   + exp2f(v4[k].z + c2[j][k].z - m) + exp2f(v4[k].w + c2[j][k].w - m);
            }
            #pragma unroll
            for (int off = 1; off < 64; off <<= 1) s += __shfl_xor(s, off);
            float u_nat = A - UNSCALE * (m + log2f(s));
            u2row[j] = u_nat * SCALE;
            dsum += fabsf(u_nat - u_old[j]);
            u_old[j] = u_nat;
        }
        if (l == 0) atomicAdd(&err[t], dsum);          // device-scope RMW: cross-XCD ok

        // ---- v partials over this wave's 4 rows -> LDS ----
        #pragma unroll
        for (int k = 0; k < 8; ++k) {
            float4 t0 = make_float4(u2row[0] + c2[0][k].x, u2row[0] + c2[0][k].y,
                                    u2row[0] + c2[0][k].z, u2row[0] + c2[0][k].w);
            float4 t1 = make_float4(u2row[1] + c2[1][k].x, u2row[1] + c2[1][k].y,
                                    u2row[1] + c2[1][k].z, u2row[1] + c2[1][k].w);
            float4 t2 = make_float4(u2row[2] + c2[2][k].x, u2row[2] + c2[2][k].y,
                                    u2row[2] + c2[2][k].z, u2row[2] + c2[2][k].w);
            float4 t3 = make_float4(u2row[3] + c2[3][k].x, u2row[3] + c2[3][k].y,
                                    u2row[3] + c2[3][k].z, u2row[3] + c2[3][k].w);
            float4 pm, ps;
            pm.x = fmaxf(fmaxf(t0.x, t1.x), fmaxf(t2.x, t3.x));
            pm.y = fmaxf(fmaxf(t0.y, t1.y), fmaxf(t2.y, t3.y));
            pm.z = fmaxf(fmaxf(t0.z, t1.z), fmaxf(t2.z, t3.z));
            pm.w = fmaxf(fmaxf(t0.w, t1.w), fmaxf(t2.w, t3.w));
            ps.x = exp2f(t0.x - pm.x) + exp2f(t1.x - pm.x) + exp2f(t2.x - pm.x) + exp2f(t3.x - pm.x);
            ps.y = exp2f(t0.y - pm.y) + exp2f(t1.y - pm.y) + exp2f(t2.y - pm.y) + exp2f(t3.y - pm.y);
            ps.z = exp2f(t0.z - pm.z) + exp2f(t1.z - pm.z) + exp2f(t2.z - pm.z) + exp2f(t3.z - pm.z);
            ps.w = exp2f(t0.w - pm.w) + exp2f(t1.w - pm.w) + exp2f(t2.w - pm.w) + exp2f(t3.w - pm.w);
            mrg[0][w][l + 64 * k] = pm;
            mrg[1][w][l + 64 * k] = ps;
        }
        __syncthreads();

        // ---- merge 2 waves -> block partial [chunk][col] float2 (coalesced) ----
        {
            float2* pout = part2 + (size_t)(bb * 256 + rc) * 2048;
            #pragma unroll
            for (int i = 0; i < 4; ++i) {
                const int c4 = tid + 128 * i;          // dense LDS read, dense global write
                float4 ma = mrg[0][0][c4], mb = mrg[0][1][c4];
                float4 sa = mrg[1][0][c4], sb = mrg[1][1][c4];
                float M0, S0, M1, S1, M2, S2, M3, S3;
                lse_merge(ma.x, sa.x, mb.x, sb.x, M0, S0);
                lse_merge(ma.y, sa.y, mb.y, sb.y, M1, S1);
                lse_merge(ma.z, sa.z, mb.z, sb.z, M2, S2);
                lse_merge(ma.w, sa.w, mb.w, sb.w, M3, S3);
                st_sys_f2(&pout[4 * c4 + 0], M0, S0);
                st_sys_f2(&pout[4 * c4 + 1], M1, S1);
                st_sys_f2(&pout[4 * c4 + 2], M2, S2);
                st_sys_f2(&pout[4 * c4 + 3], M3, S3);
            }
        }

        gbar(bar, NBLK * (++ep));                      // partials visible

        // ---- distributed combine: 8 cols/block, 16 lanes/col x 16 chunks ----
        {
            const int ci  = tid >> 4;                  // 0..7
            const int sub = tid & 15;
            const int g   = bid * 8 + ci;              // 0..8191
            const int b2  = g >> 11, c = g & (P - 1);
            const float2* pb = part2 + (size_t)b2 * 256 * 2048 + c;
            float M = -1e30f, S = 0.0f;
            #pragma unroll
            for (int q = 0; q < 16; ++q) {
                const int ch = sub * 16 + q;
                float2 pk = ld_sys_f2(pb + (size_t)ch * 2048);
                float m2 = fmaxf(M, pk.x);
                S = S * exp2f(M - m2) + pk.y * exp2f(pk.x - m2);
                M = m2;
            }
            #pragma unroll
            for (int off = 1; off < 16; off <<= 1) {
                float pm = __shfl_xor(M, off);
                float ps = __shfl_xor(S, off);
                float m2 = fmaxf(M, pm);
                S = S * exp2f(M - m2) + ps * exp2f(pm - m2);
                M = m2;
            }
            if (sub == 0)
                st_sys_f(&v2s[g], (A - UNSCALE * (M + log2f(S))) * SCALE);
        }

        gbar(bar, NBLK * (++ep));                      // v visible

        if (ld_sys_f(&err[t]) < 4.0f * THRESH) break;  // uniform device-side break
    }

    // ---- fused epilogue: pi = exp((u+v-C)/eps), cost = sum pi*C ----
    {
        {
            unsigned long long* vl = (unsigned long long*)v_lds;
            const unsigned long long* vg = (const unsigned long long*)(v2s + bb * P);
            #pragma unroll
            for (int i = 0; i < 8; ++i)
                vl[tid + 128 * i] = ld_sys_u64(&vg[tid + 128 * i]);
        }
        __syncthreads();
        #pragma unroll
        for (int k = 0; k < 8; ++k) v4[k] = ((const float4*)v_lds)[l + 64 * k];

        float* cost = out;
        float* pi   = out + B;
        float lc = 0.0f;
        #pragma unroll
        for (int j = 0; j < 4; ++j) {
            const int r = row0 + w * 4 + j;
            float4* Prow = (float4*)(pi + (size_t)(bb * P + r) * P);
            const float u2 = u2row[j];
            #pragma unroll
            for (int k = 0; k < 8; ++k) {
                float4 p, cc;
                cc.x = -UNSCALE * c2[j][k].x;          // recover C from register copy
                cc.y = -UNSCALE * c2[j][k].y;
                cc.z = -UNSCALE * c2[j][k].z;
                cc.w = -UNSCALE * c2[j][k].w;
                p.x = exp2f(u2 + v4[k].x + c2[j][k].x);
                p.y = exp2f(u2 + v4[k].y + c2[j][k].y);
                p.z = exp2f(u2 + v4[k].z + c2[j][k].z);
                p.w = exp2f(u2 + v4[k].w + c2[j][k].w);
                lc = fmaf(p.x, cc.x, lc); lc = fmaf(p.y, cc.y, lc);
                lc = fmaf(p.z, cc.z, lc); lc = fmaf(p.w, cc.w, lc);
                Prow[l + 64 * k] = p;
            }
        }
        #pragma unroll
        for (int off = 1; off < 64; off <<= 1) lc += __shfl_xor(lc, off);
        __syncthreads();
        float* sm = v_lds;                             // reuse LDS for 2-wave reduce
        if (l == 0) sm[w] = lc;
        __syncthreads();
        if (tid == 0) atomicAdd(&cost[bb], sm[0] + sm[1]);
    }
}

// ============ fallback path (proven multi-kernel, 7704 us) ============
__global__ __launch_bounds__(256, 2)
void iter_kernel(const float* __restrict__ C, float* __restrict__ part_m,
                 float* __restrict__ part_s, float* __restrict__ ws, int t)
{
    float* u2s = ws + WS_U;
    float* v2s = ws + WS_V;
    float* uo  = ws + WS_UO;
    float* err = ws + WS_ERR;
    if (t > 0 && err[t - 1] < 4.0f * THRESH) return;

    const int bid = blockIdx.x, tid = threadIdx.x;
    const int w = tid >> 6, l = tid & 63;
    const int bb = bid >> 7, rc = bid & 127;
    const int row0 = rc * 16;
    const int baserow = bb * P + row0 + w * 4;

    __shared__ float4 m_lds[4 * 512];
    __shared__ float4 s_lds[4 * 512];

    const float A = EPS * __logf(1.0f / (float)P + 1e-8f);

    const float4* vv = (const float4*)(v2s + bb * P);
    float4 v4[8];
    #pragma unroll
    for (int k = 0; k < 8; ++k) v4[k] = vv[l + 64 * k];

    float4 c2[4][8];
    #pragma unroll
    for (int j = 0; j < 4; ++j) {
        const float4* Crow = (const float4*)(C + (size_t)(baserow + j) * P);
        #pragma unroll
        for (int k = 0; k < 8; ++k) {
            float4 cc = Crow[l + 64 * k];
            c2[j][k] = make_float4(-SCALE * cc.x, -SCALE * cc.y,
                                   -SCALE * cc.z, -SCALE * cc.w);
        }
    }

    float u2row[4];
    float dsum = 0.0f;
    #pragma unroll
    for (int j = 0; j < 4; ++j) {
        float m = -1e30f;
        #pragma unroll
        for (int k = 0; k < 8; ++k) {
            float4 tt = make_float4(v4[k].x + c2[j][k].x, v4[k].y + c2[j][k].y,
                                    v4[k].z + c2[j][k].z, v4[k].w + c2[j][k].w);
            m = fmaxf(m, max4(tt));
        }
        #pragma unroll
        for (int off = 1; off < 64; off <<= 1) m = fmaxf(m, __shfl_xor(m, off));
        float s = 0.0f;
        #pragma unroll
        for (int k = 0; k < 8; ++k) {
            s += exp2f(v4[k].x + c2[j][k].x - m) + exp2f(v4[k].y + c2[j][k].y - m)
               + exp2f(v4[k].z + c2[j][k].z - m) + exp2f(v4[k].w + c2[j][k].w - m);
        }
        #pragma unroll
        for (int off = 1; off < 64; off <<= 1) s += __shfl_xor(s, off);
        float u_nat = A - UNSCALE * (m + log2f(s));
        u2row[j] = u_nat * SCALE;
        if (l == 0) {
            const int rg = baserow + j;
            dsum += fabsf(u_nat - uo[rg]);
            uo[rg]  = u_nat;
            u2s[rg] = u2row[j];
        }
    }
    if (l == 0) atomicAdd(&err[t], dsum);

    #pragma unroll
    for (int k = 0; k < 8; ++k) {
        float4 t0 = make_float4(u2row[0] + c2[0][k].x, u2row[0] + c2[0][k].y,
                                u2row[0] + c2[0][k].z, u2row[0] + c2[0][k].w);
        float4 t1 = make_float4(u2row[1] + c2[1][k].x, u2row[1] + c2[1][k].y,
                                u2row[1] + c2[1][k].z, u2row[1] + c2[1][k].w);
        float4 t2 = make_float4(u2row[2] + c2[2][k].x, u2row[2] + c2[2][k].y,
                                u2row[2] + c2[2][k].z, u2row[2] + c2[2][k].w);
        float4 t3 = make_float4(u2row[3] + c2[3][k].x, u2row[3] + c2[3][k].y,
                                u2row[3] + c2[3][k].z, u2row[3] + c2[3][k].w);
        float4 pm, ps;
        pm.x = fmaxf(fmaxf(t0.x, t1.x), fmaxf(t2.x, t3.x));
        pm.y = fmaxf(fmaxf(t0.y, t1.y), fmaxf(t2.y, t3.y));
        pm.z = fmaxf(fmaxf(t0.z, t1.z), fmaxf(t2.z, t3.z));
        pm.w = fmaxf(fmaxf(t0.w, t1.w), fmaxf(t2.w, t3.w));
        ps.x = exp2f(t0.x - pm.x) + exp2f(t1.x - pm.x) + exp2f(t2.x - pm.x) + exp2f(t3.x - pm.x);
        ps.y = exp2f(t0.y - pm.y) + exp2f(t1.y - pm.y) + exp2f(t2.y - pm.y) + exp2f(t3.y - pm.y);
        ps.z = exp2f(t0.z - pm.z) + exp2f(t1.z - pm.z) + exp2f(t2.z - pm.z) + exp2f(t3.z - pm.z);
        ps.w = exp2f(t0.w - pm.w) + exp2f(t1.w - pm.w) + exp2f(t2.w - pm.w) + exp2f(t3.w - pm.w);
        m_lds[w * 512 + l + 64 * k] = pm;
        s_lds[w * 512 + l + 64 * k] = ps;
    }
    __syncthreads();

    float4* pm_out = ((float4*)part_m) + (size_t)bid * 512;
    float4* ps_out = ((float4*)part_s) + (size_t)bid * 512;
    #pragma unroll
    for (int h = 0; h < 2; ++h) {
        const int idx = tid * 2 + h;
        float4 M = m_lds[idx], S = s_lds[idx];
        #pragma unroll
        for (int q = 1; q < 4; ++q) {
            float4 pm = m_lds[q * 512 + idx], ps = s_lds[q * 512 + idx];
            float m2;
            m2 = fmaxf(M.x, pm.x); S.x = S.x * exp2f(M.x - m2) + ps.x * exp2f(pm.x - m2); M.x = m2;
            m2 = fmaxf(M.y, pm.y); S.y = S.y * exp2f(M.y - m2) + ps.y * exp2f(pm.y - m2); M.y = m2;
            m2 = fmaxf(M.z, pm.z); S.z = S.z * exp2f(M.z - m2) + ps.z * exp2f(pm.z - m2); M.z = m2;
            m2 = fmaxf(M.w, pm.w); S.w = S.w * exp2f(M.w - m2) + ps.w * exp2f(pm.w - m2); M.w = m2;
        }
        pm_out[idx] = M;
        ps_out[idx] = S;
    }
}

__global__ __launch_bounds__(256)
void comb_kernel(const float* __restrict__ part_m, const float* __restrict__ part_s,
                 float* __restrict__ ws, int t)
{
    float* v2s = ws + WS_V;
    float* err = ws + WS_ERR;
    if (t > 0 && err[t - 1] < 4.0f * THRESH) return;

    const int g = blockIdx.x * 256 + threadIdx.x;
    const int b = g >> 11, c = g & (P - 1);
    const float* pmb = part_m + (size_t)(b * 128) * P + c;
    const float* psb = part_s + (size_t)(b * 128) * P + c;

    const float A = EPS * __logf(1.0f / (float)P + 1e-8f);

    float M = -1e30f;
    #pragma unroll 8
    for (int q = 0; q < 128; ++q) M = fmaxf(M, pmb[(size_t)q * P]);
    float S = 0.0f;
    #pragma unroll 8
    for (int q = 0; q < 128; ++q)
        S = fmaf(psb[(size_t)q * P], exp2f(pmb[(size_t)q * P] - M), S);

    float v_nat = A - UNSCALE * (M + log2f(S));
    v2s[g] = v_nat * SCALE;
}

__global__ __launch_bounds__(256)
void epi_kernel(float* __restrict__ out, const float* __restrict__ ws)
{
    const float* u2s = ws + WS_U;
    const float* v2s = ws + WS_V;
    float* cost = out;
    float* pi   = out + B;
    const float* C = out + B + (size_t)B * P * P;

    const int bid = blockIdx.x, tid = threadIdx.x;
    const int w = tid >> 6, l = tid & 63;
    const int bb = bid >> 7, rc = bid & 127;
    const int row0 = rc * 16;

    const float4* vv = (const float4*)(v2s + bb * P);
    float4 v4[8];
    #pragma unroll
    for (int k = 0; k < 8; ++k) v4[k] = vv[l + 64 * k];

    float lc = 0.0f;
    #pragma unroll
    for (int j = 0; j < 4; ++j) {
        const int r = row0 + w * 4 + j;
        const float u2 = u2s[bb * P + r];
        const float4* Crow = (const float4*)(C  + (size_t)(bb * P + r) * P);
        float4*       Prow = (float4*)      (pi + (size_t)(bb * P + r) * P);
        #pragma unroll
        for (int k = 0; k < 8; ++k) {
            float4 cc = Crow[l + 64 * k];
            float4 p;
            p.x = exp2f(u2 + v4[k].x - SCALE * cc.x);
            p.y = exp2f(u2 + v4[k].y - SCALE * cc.y);
            p.z = exp2f(u2 + v4[k].z - SCALE * cc.z);
            p.w = exp2f(u2 + v4[k].w - SCALE * cc.w);
            lc = fmaf(p.x, cc.x, lc); lc = fmaf(p.y, cc.y, lc);
            lc = fmaf(p.z, cc.z, lc); lc = fmaf(p.w, cc.w, lc);
            Prow[l + 64 * k] = p;
        }
    }
    #pragma unroll
    for (int off = 1; off < 64; off <<= 1) lc += __shfl_xor(lc, off);
    __shared__ float sm[4];
    if (l == 0) sm[w] = lc;
    __syncthreads();
    if (tid == 0) atomicAdd(&cost[bb], sm[0] + sm[1] + sm[2] + sm[3]);
}

extern "C" void kernel_launch(void* const* d_in, const int* in_sizes, int n_in,
                              void* d_out, int out_size, void* d_ws, size_t ws_size,
                              hipStream_t stream) {
    const float* x = (const float*)d_in[0];
    const float* y = (const float*)d_in[1];
    float* out = (float*)d_out;
    float* ws  = (float*)d_ws;
    const float* C = out + B + (size_t)B * P * P;
    // persist partials: [batch][chunk 256][col 2048] float2 = 16 MB, inside pi region
    float2* part2 = (float2*)(out + B);
    // fallback partials (same region, old layout)
    float* part_m = out + B;
    float* part_s = part_m + 512 * P;

    prep_kernel<<<2048, 256, 0, stream>>>(x, y, out, ws);

    void* args[] = { (void*)&C, (void*)&part2, (void*)&ws, (void*)&out };
    hipError_t e = hipLaunchCooperativeKernel((void*)persist_kernel,
                                              dim3(NBLK), dim3(NTHR),
                                              args, 0, stream);
    if (e != hipSuccess) {
        for (int t = 0; t < MAX_ITER; ++t) {
            iter_kernel<<<512, 256, 0, stream>>>(C, part_m, part_s, ws, t);
            comb_kernel<<<32,  256, 0, stream>>>(part_m, part_s, ws, t);
        }
        epi_kernel<<<512, 256, 0, stream>>>(out, ws);
    }
}

// Round 5
// 2150.478 us; speedup vs baseline: 6.8802x; 6.7104x over previous
//
#include <hip/hip_runtime.h>
#include <cmath>

// Problem constants (match reference)
constexpr int   B        = 4;
constexpr int   P        = 2048;   // P1 == P2
constexpr int   D        = 64;
constexpr float EPS      = 0.1f;
constexpr float THRESH   = 0.1f;
constexpr int   MAX_ITER = 100;

constexpr float LOG2E   = 1.44269504088896340736f;
constexpr float LN2     = 0.69314718055994530942f;
constexpr float SCALE   = LOG2E / EPS;   // natural -> log2 domain, /eps folded in
constexpr float UNSCALE = EPS * LN2;     // inverse

// ws layout (floats): u2s[8192] | v2s[8192] | uo[8192] (fallback) / bar (persist) | err[128]
constexpr int WS_U   = 0;
constexpr int WS_V   = 8192;
constexpr int WS_UO  = 16384;   // fallback-only; persist reuses as barrier region
constexpr int WS_BARX = 16384;  // ~1100 u32 words, zeroed by prep
constexpr int WS_ERR = 24576;
constexpr int WS_FLOATS = 24712;

constexpr int NBLK = 256;    // persistent grid: 1 block/CU
constexpr int NTHR = 512;    // 8 waves x 4 rows = 32 rows/block

typedef float f32x4 __attribute__((ext_vector_type(4)));   // native 4xVGPR tuple for asm

__device__ __forceinline__ float max4(float4 a) {
    return fmaxf(fmaxf(a.x, a.y), fmaxf(a.z, a.w));
}

// ---- system-scope (cross-XCD coherent, L2-bypassing) access helpers ----
__device__ __forceinline__ float ld_sys_f(const float* p) {
    return __hip_atomic_load((float*)p, __ATOMIC_RELAXED, __HIP_MEMORY_SCOPE_SYSTEM);
}
__device__ __forceinline__ void st_sys_f2(float2* p, float m, float s) {
    union { float2 f; unsigned long long u; } pk;
    pk.f.x = m; pk.f.y = s;
    __hip_atomic_store((unsigned long long*)p, pk.u, __ATOMIC_RELAXED, __HIP_MEMORY_SCOPE_SYSTEM);
}
// 16-byte system-scope ops (sc0 sc1): full-sector writes kill the 4x amplification
// that 8-byte atomic stores showed in rounds 2/3 (WRITE_SIZE = 4x payload).
// NOTE: must use ext_vector_type, NOT HIP float4 (struct) — the 'v' constraint
// rejects indirect (memory) operands (round-4 compile failure).
__device__ __forceinline__ float4 ld_sys_f4(const float4* p) {
    f32x4 r;
    asm volatile("global_load_dwordx4 %0, %1, off sc0 sc1\n\ts_waitcnt vmcnt(0)"
                 : "=v"(r) : "v"(p) : "memory");
    return make_float4(r.x, r.y, r.z, r.w);
}
__device__ __forceinline__ void st_sys_f4(float4* p, float4 v) {
    f32x4 t;
    t.x = v.x; t.y = v.y; t.z = v.z; t.w = v.w;
    asm volatile("global_store_dwordx4 %0, %1, off sc0 sc1"
                 :: "v"(p), "v"(t) : "memory");
}

// ---- hierarchical fence-free grid barrier ----
// 16 groups x 16 blocks; counters/release words 128 B apart. <=16 pollers per
// line (vs 1024 on one line in rounds 2/3 -> arrival atomics queued behind
// polls). Monotonic epochs, no reset. All cross-block data moves via sc0sc1,
// so no L2 writeback/invalidate is needed (mechanism proven r2/r3).
__device__ __forceinline__ void gbar(unsigned* bar, unsigned ep) {
    asm volatile("s_waitcnt vmcnt(0)" ::: "memory");   // drain this wave's stores
    __syncthreads();
    if (threadIdx.x == 0) {
        const int g = blockIdx.x & 15;
        unsigned* gc   = bar + g * 32;
        unsigned* root = bar + 512;
        unsigned* rel  = bar + 544 + g * 32;
        unsigned a = __hip_atomic_fetch_add(gc, 1u, __ATOMIC_RELAXED,
                                            __HIP_MEMORY_SCOPE_SYSTEM);
        if (a == ep * 16u - 1u) {                      // last arrival in group
            unsigned r = __hip_atomic_fetch_add(root, 1u, __ATOMIC_RELAXED,
                                                __HIP_MEMORY_SCOPE_SYSTEM);
            if (r == ep * 16u - 1u) {                  // global last
                #pragma unroll
                for (int j = 0; j < 16; ++j)
                    __hip_atomic_store(bar + 544 + j * 32, ep, __ATOMIC_RELAXED,
                                       __HIP_MEMORY_SCOPE_SYSTEM);
            }
        }
        while (__hip_atomic_load(rel, __ATOMIC_RELAXED,
                                 __HIP_MEMORY_SCOPE_SYSTEM) < ep)
            __builtin_amdgcn_s_sleep(16);
    }
    __syncthreads();
}

__device__ __forceinline__ void lse_merge(float ma, float sa, float mb, float sb,
                                          float& M, float& S) {
    float m2 = fmaxf(ma, mb);
    S = sa * exp2f(ma - m2) + sb * exp2f(mb - m2);
    M = m2;
}

// ============ prep: C = sum_d (x-y)^2, register-tiled; zero scratch ============
__global__ __launch_bounds__(256)
void prep_kernel(const float* __restrict__ x, const float* __restrict__ y,
                 float* __restrict__ out, float* __restrict__ ws)
{
    const int bid = blockIdx.x, tid = threadIdx.x;
    const int bb = bid >> 9, tr = (bid >> 4) & 31, tc = bid & 15;
    const int row0 = tr * 64, col0 = tc * 128;

    if (bid == 0) {
        for (int i = tid; i < WS_FLOATS; i += 256) ws[i] = 0.0f;
        if (tid < B) out[tid] = 0.0f;
    }

    __shared__ float xs[64 * 65];
    __shared__ float ys[128 * 65];
    for (int i = tid; i < 64 * 64; i += 256) {
        int r = i >> 6, d = i & 63;
        xs[r * 65 + d] = x[(size_t)(bb * P + row0 + r) * D + d];
    }
    for (int i = tid; i < 128 * 64; i += 256) {
        int c = i >> 6, d = i & 63;
        ys[c * 65 + d] = y[(size_t)(bb * P + col0 + c) * D + d];
    }
    __syncthreads();

    const int tx = tid & 15, ty = tid >> 4;
    float acc[4][8];
    #pragma unroll
    for (int j = 0; j < 4; ++j)
        #pragma unroll
        for (int i = 0; i < 8; ++i) acc[j][i] = 0.0f;

    #pragma unroll 4
    for (int k = 0; k < 64; ++k) {
        float xa[4], yb[8];
        #pragma unroll
        for (int j = 0; j < 4; ++j) xa[j] = xs[(ty * 4 + j) * 65 + k];
        #pragma unroll
        for (int i = 0; i < 8; ++i) yb[i] = ys[(tx * 8 + i) * 65 + k];
        #pragma unroll
        for (int j = 0; j < 4; ++j)
            #pragma unroll
            for (int i = 0; i < 8; ++i) {
                float d = xa[j] - yb[i];
                acc[j][i] = fmaf(d, d, acc[j][i]);
            }
    }

    float* C_out = out + B + (size_t)B * P * P;
    #pragma unroll
    for (int j = 0; j < 4; ++j) {
        size_t base = (size_t)(bb * P + row0 + ty * 4 + j) * P + col0 + tx * 8;
        float4 a0 = make_float4(acc[j][0], acc[j][1], acc[j][2], acc[j][3]);
        float4 a1 = make_float4(acc[j][4], acc[j][5], acc[j][6], acc[j][7]);
        ((float4*)&C_out[base])[0] = a0;
        ((float4*)&C_out[base])[1] = a1;
    }
}

// ============ persistent kernel v4: 256 blocks x 512 thr, 32 rows/block ============
// Per-wave inner code identical to the proven version (4 rows x 2048 cols/wave).
// Changes vs r3: 4x fewer chunks (64/batch) -> partial payload 4.2 MB/iter;
// 16 B sc stores/loads (no sector amplification); hierarchical barrier;
// per-block err reduce (256 RMWs/iter, not 2048).
// partials layout: part4[batch][colpair 1024][chunk 64] float4=(m0,s0,m1,s1)
__global__ __attribute__((amdgpu_flat_work_group_size(NTHR, NTHR),
                          amdgpu_waves_per_eu(2, 2)))
void persist_kernel(const float* C, float4* part4, float* ws, float* out)
{
    float* v2s = ws + WS_V;
    float* err = ws + WS_ERR;
    unsigned* bar = (unsigned*)(ws + WS_BARX);

    const int bid = blockIdx.x, tid = threadIdx.x;
    const int w = tid >> 6, l = tid & 63;
    const int bb = bid >> 6, rc = bid & 63;          // 64 chunks of 32 rows per batch
    const int row0 = rc * 32;
    const int baserow = bb * P + row0 + w * 4;

    __shared__ float4 qm[8][128];                    // 16 KB quarter m-planes
    __shared__ float4 qs[8][128];                    // 16 KB quarter s-planes
    __shared__ float4 vbuf[512];                     // 8 KB v staging
    __shared__ float  esm[8];

    const float A = EPS * __logf(1.0f / (float)P + 1e-8f);

    // ---- load C tile ONCE, pre-scaled: c2 = -C/eps*log2e ----
    float4 c2[4][8];
    #pragma unroll
    for (int j = 0; j < 4; ++j) {
        const float4* Crow = (const float4*)(C + (size_t)(baserow + j) * P);
        #pragma unroll
        for (int k = 0; k < 8; ++k) {
            float4 cc = Crow[l + 64 * k];
            c2[j][k] = make_float4(-SCALE * cc.x, -SCALE * cc.y,
                                   -SCALE * cc.z, -SCALE * cc.w);
        }
    }
    #pragma unroll
    for (int j = 0; j < 4; ++j)
        #pragma unroll
        for (int k = 0; k < 8; ++k)
            asm volatile("" : "+v"(c2[j][k].x), "+v"(c2[j][k].y),
                              "+v"(c2[j][k].z), "+v"(c2[j][k].w));

    float u_old[4] = {0.0f, 0.0f, 0.0f, 0.0f};
    float u2row[4] = {0.0f, 0.0f, 0.0f, 0.0f};
    float4 v4[8];
    unsigned ep = 0;

    for (int t = 0; t < MAX_ITER; ++t) {
        // ---- stage v (16 B sc loads, coalesced) -> LDS -> regs ----
        {
            const float4* vg = (const float4*)(v2s + bb * P);
            vbuf[tid] = ld_sys_f4(&vg[tid]);
        }
        __syncthreads();
        #pragma unroll
        for (int k = 0; k < 8; ++k) v4[k] = vbuf[l + 64 * k];

        // ---- u update per row (exact max-then-sum LSE, all-register) ----
        float dsum = 0.0f;
        #pragma unroll
        for (int j = 0; j < 4; ++j) {
            float m = -1e30f;
            #pragma unroll
            for (int k = 0; k < 8; ++k) {
                float4 tt = make_float4(v4[k].x + c2[j][k].x, v4[k].y + c2[j][k].y,
                                        v4[k].z + c2[j][k].z, v4[k].w + c2[j][k].w);
                m = fmaxf(m, max4(tt));
            }
            #pragma unroll
            for (int off = 1; off < 64; off <<= 1) m = fmaxf(m, __shfl_xor(m, off));
            float s = 0.0f;
            #pragma unroll
            for (int k = 0; k < 8; ++k) {
                s += exp2f(v4[k].x + c2[j][k].x - m) + exp2f(v4[k].y + c2[j][k].y - m)
                   + exp2f(v4[k].z + c2[j][k].z - m) + exp2f(v4[k].w + c2[j][k].w - m);
            }
            #pragma unroll
            for (int off = 1; off < 64; off <<= 1) s += __shfl_xor(s, off);
            float u_nat = A - UNSCALE * (m + log2f(s));
            u2row[j] = u_nat * SCALE;
            dsum += fabsf(u_nat - u_old[j]);
            u_old[j] = u_nat;
        }

        // ---- v partials: column-quarter pipeline over LDS ----
        #pragma unroll
        for (int q = 0; q < 4; ++q) {
            #pragma unroll
            for (int h = 0; h < 2; ++h) {
                const int k = 2 * q + h;
                float4 t0 = make_float4(u2row[0] + c2[0][k].x, u2row[0] + c2[0][k].y,
                                        u2row[0] + c2[0][k].z, u2row[0] + c2[0][k].w);
                float4 t1 = make_float4(u2row[1] + c2[1][k].x, u2row[1] + c2[1][k].y,
                                        u2row[1] + c2[1][k].z, u2row[1] + c2[1][k].w);
                float4 t2 = make_float4(u2row[2] + c2[2][k].x, u2row[2] + c2[2][k].y,
                                        u2row[2] + c2[2][k].z, u2row[2] + c2[2][k].w);
                float4 t3 = make_float4(u2row[3] + c2[3][k].x, u2row[3] + c2[3][k].y,
                                        u2row[3] + c2[3][k].z, u2row[3] + c2[3][k].w);
                float4 pm, ps;
                pm.x = fmaxf(fmaxf(t0.x, t1.x), fmaxf(t2.x, t3.x));
                pm.y = fmaxf(fmaxf(t0.y, t1.y), fmaxf(t2.y, t3.y));
                pm.z = fmaxf(fmaxf(t0.z, t1.z), fmaxf(t2.z, t3.z));
                pm.w = fmaxf(fmaxf(t0.w, t1.w), fmaxf(t2.w, t3.w));
                ps.x = exp2f(t0.x - pm.x) + exp2f(t1.x - pm.x) + exp2f(t2.x - pm.x) + exp2f(t3.x - pm.x);
                ps.y = exp2f(t0.y - pm.y) + exp2f(t1.y - pm.y) + exp2f(t2.y - pm.y) + exp2f(t3.y - pm.y);
                ps.z = exp2f(t0.z - pm.z) + exp2f(t1.z - pm.z) + exp2f(t2.z - pm.z) + exp2f(t3.z - pm.z);
                ps.w = exp2f(t0.w - pm.w) + exp2f(t1.w - pm.w) + exp2f(t2.w - pm.w) + exp2f(t3.w - pm.w);
                qm[w][l + 64 * h] = pm;
                qs[w][l + 64 * h] = ps;
            }
            if (q == 0 && l == 0) esm[w] = dsum;
            __syncthreads();
            if (q == 0 && tid == 0) {
                float e = 0.0f;
                #pragma unroll
                for (int i = 0; i < 8; ++i) e += esm[i];
                atomicAdd(&err[t], e);                 // one RMW per block
            }
            // fold 8 waves for scalar col (512q + tid)
            {
                const float* qmf = (const float*)qm;
                const float* qsf = (const float*)qs;
                float M = qmf[tid], S = qsf[tid];
                #pragma unroll
                for (int ww = 1; ww < 8; ++ww)
                    lse_merge(M, S, qmf[ww * 512 + tid], qsf[ww * 512 + tid], M, S);
                // pair columns via lane exchange -> one 16 B store per even lane
                float m1 = __shfl_xor(M, 1), s1 = __shfl_xor(S, 1);
                if ((tid & 1) == 0) {
                    const int cp = 256 * q + (tid >> 1);
                    st_sys_f4(&part4[((size_t)bb * 1024 + cp) * 64 + rc],
                              make_float4(M, S, m1, s1));
                }
            }
            __syncthreads();
        }

        gbar(bar, ++ep);                               // partials visible

        // ---- distributed combine: 16 colpairs/block, 32 lanes x 2 chunks ----
        {
            const int pi_ = tid >> 5, q32 = tid & 31;
            const int gp  = bid * 16 + pi_;            // 0..4095 colpairs
            const int bb2 = gp >> 10, cp2 = gp & 1023;
            const float4* base = part4 + ((size_t)bb2 * 1024 + cp2) * 64;
            float4 a  = ld_sys_f4(base + q32);         // contiguous across lanes
            float4 b_ = ld_sys_f4(base + q32 + 32);
            float M0 = a.x, S0 = a.y, M1 = a.z, S1 = a.w;
            lse_merge(M0, S0, b_.x, b_.y, M0, S0);
            lse_merge(M1, S1, b_.z, b_.w, M1, S1);
            #pragma unroll
            for (int off = 16; off >= 1; off >>= 1) {  // fold 32-lane group
                float pm0 = __shfl_xor(M0, off), ps0 = __shfl_xor(S0, off);
                float pm1 = __shfl_xor(M1, off), ps1 = __shfl_xor(S1, off);
                lse_merge(M0, S0, pm0, ps0, M0, S0);
                lse_merge(M1, S1, pm1, ps1, M1, S1);
            }
            if (q32 == 0) {
                float v0 = (A - UNSCALE * (M0 + log2f(S0))) * SCALE;
                float v1 = (A - UNSCALE * (M1 + log2f(S1))) * SCALE;
                st_sys_f2((float2*)&v2s[bb2 * 2048 + 2 * cp2], v0, v1);
            }
        }

        gbar(bar, ++ep);                               // v visible

        if (ld_sys_f(&err[t]) < 4.0f * THRESH) break;  // uniform device-side break
    }

    // ---- fused epilogue: pi = exp((u+v-C)/eps), cost = sum pi*C ----
    {
        {
            const float4* vg = (const float4*)(v2s + bb * P);
            vbuf[tid] = ld_sys_f4(&vg[tid]);
        }
        __syncthreads();
        #pragma unroll
        for (int k = 0; k < 8; ++k) v4[k] = vbuf[l + 64 * k];

        float* cost = out;
        float* pi   = out + B;
        float lc = 0.0f;
        #pragma unroll
        for (int j = 0; j < 4; ++j) {
            const int r = row0 + w * 4 + j;
            float4* Prow = (float4*)(pi + (size_t)(bb * P + r) * P);
            const float u2 = u2row[j];
            #pragma unroll
            for (int k = 0; k < 8; ++k) {
                float4 p, cc;
                cc.x = -UNSCALE * c2[j][k].x;          // recover C from register copy
                cc.y = -UNSCALE * c2[j][k].y;
                cc.z = -UNSCALE * c2[j][k].z;
                cc.w = -UNSCALE * c2[j][k].w;
                p.x = exp2f(u2 + v4[k].x + c2[j][k].x);
                p.y = exp2f(u2 + v4[k].y + c2[j][k].y);
                p.z = exp2f(u2 + v4[k].z + c2[j][k].z);
                p.w = exp2f(u2 + v4[k].w + c2[j][k].w);
                lc = fmaf(p.x, cc.x, lc); lc = fmaf(p.y, cc.y, lc);
                lc = fmaf(p.z, cc.z, lc); lc = fmaf(p.w, cc.w, lc);
                Prow[l + 64 * k] = p;
            }
        }
        #pragma unroll
        for (int off = 1; off < 64; off <<= 1) lc += __shfl_xor(lc, off);
        __syncthreads();
        if (l == 0) esm[w] = lc;
        __syncthreads();
        if (tid == 0) {
            float e = 0.0f;
            #pragma unroll
            for (int i = 0; i < 8; ++i) e += esm[i];
            atomicAdd(&cost[bb], e);
        }
    }
}

// ============ fallback path (proven multi-kernel, 7704 us) ============
__global__ __launch_bounds__(256, 2)
void iter_kernel(const float* __restrict__ C, float* __restrict__ part_m,
                 float* __restrict__ part_s, float* __restrict__ ws, int t)
{
    float* u2s = ws + WS_U;
    float* v2s = ws + WS_V;
    float* uo  = ws + WS_UO;
    float* err = ws + WS_ERR;
    if (t > 0 && err[t - 1] < 4.0f * THRESH) return;

    const int bid = blockIdx.x, tid = threadIdx.x;
    const int w = tid >> 6, l = tid & 63;
    const int bb = bid >> 7, rc = bid & 127;
    const int row0 = rc * 16;
    const int baserow = bb * P + row0 + w * 4;

    __shared__ float4 m_lds[4 * 512];
    __shared__ float4 s_lds[4 * 512];

    const float A = EPS * __logf(1.0f / (float)P + 1e-8f);

    const float4* vv = (const float4*)(v2s + bb * P);
    float4 v4[8];
    #pragma unroll
    for (int k = 0; k < 8; ++k) v4[k] = vv[l + 64 * k];

    float4 c2[4][8];
    #pragma unroll
    for (int j = 0; j < 4; ++j) {
        const float4* Crow = (const float4*)(C + (size_t)(baserow + j) * P);
        #pragma unroll
        for (int k = 0; k < 8; ++k) {
            float4 cc = Crow[l + 64 * k];
            c2[j][k] = make_float4(-SCALE * cc.x, -SCALE * cc.y,
                                   -SCALE * cc.z, -SCALE * cc.w);
        }
    }

    float u2row[4];
    float dsum = 0.0f;
    #pragma unroll
    for (int j = 0; j < 4; ++j) {
        float m = -1e30f;
        #pragma unroll
        for (int k = 0; k < 8; ++k) {
            float4 tt = make_float4(v4[k].x + c2[j][k].x, v4[k].y + c2[j][k].y,
                                    v4[k].z + c2[j][k].z, v4[k].w + c2[j][k].w);
            m = fmaxf(m, max4(tt));
        }
        #pragma unroll
        for (int off = 1; off < 64; off <<= 1) m = fmaxf(m, __shfl_xor(m, off));
        float s = 0.0f;
        #pragma unroll
        for (int k = 0; k < 8; ++k) {
            s += exp2f(v4[k].x + c2[j][k].x - m) + exp2f(v4[k].y + c2[j][k].y - m)
               + exp2f(v4[k].z + c2[j][k].z - m) + exp2f(v4[k].w + c2[j][k].w - m);
        }
        #pragma unroll
        for (int off = 1; off < 64; off <<= 1) s += __shfl_xor(s, off);
        float u_nat = A - UNSCALE * (m + log2f(s));
        u2row[j] = u_nat * SCALE;
        if (l == 0) {
            const int rg = baserow + j;
            dsum += fabsf(u_nat - uo[rg]);
            uo[rg]  = u_nat;
            u2s[rg] = u2row[j];
        }
    }
    if (l == 0) atomicAdd(&err[t], dsum);

    #pragma unroll
    for (int k = 0; k < 8; ++k) {
        float4 t0 = make_float4(u2row[0] + c2[0][k].x, u2row[0] + c2[0][k].y,
                                u2row[0] + c2[0][k].z, u2row[0] + c2[0][k].w);
        float4 t1 = make_float4(u2row[1] + c2[1][k].x, u2row[1] + c2[1][k].y,
                                u2row[1] + c2[1][k].z, u2row[1] + c2[1][k].w);
        float4 t2 = make_float4(u2row[2] + c2[2][k].x, u2row[2] + c2[2][k].y,
                                u2row[2] + c2[2][k].z, u2row[2] + c2[2][k].w);
        float4 t3 = make_float4(u2row[3] + c2[3][k].x, u2row[3] + c2[3][k].y,
                                u2row[3] + c2[3][k].z, u2row[3] + c2[3][k].w);
        float4 pm, ps;
        pm.x = fmaxf(fmaxf(t0.x, t1.x), fmaxf(t2.x, t3.x));
        pm.y = fmaxf(fmaxf(t0.y, t1.y), fmaxf(t2.y, t3.y));
        pm.z = fmaxf(fmaxf(t0.z, t1.z), fmaxf(t2.z, t3.z));
        pm.w = fmaxf(fmaxf(t0.w, t1.w), fmaxf(t2.w, t3.w));
        ps.x = exp2f(t0.x - pm.x) + exp2f(t1.x - pm.x) + exp2f(t2.x - pm.x) + exp2f(t3.x - pm.x);
        ps.y = exp2f(t0.y - pm.y) + exp2f(t1.y - pm.y) + exp2f(t2.y - pm.y) + exp2f(t3.y - pm.y);
        ps.z = exp2f(t0.z - pm.z) + exp2f(t1.z - pm.z) + exp2f(t2.z - pm.z) + exp2f(t3.z - pm.z);
        ps.w = exp2f(t0.w - pm.w) + exp2f(t1.w - pm.w) + exp2f(t2.w - pm.w) + exp2f(t3.w - pm.w);
        m_lds[w * 512 + l + 64 * k] = pm;
        s_lds[w * 512 + l + 64 * k] = ps;
    }
    __syncthreads();

    float4* pm_out = ((float4*)part_m) + (size_t)bid * 512;
    float4* ps_out = ((float4*)part_s) + (size_t)bid * 512;
    #pragma unroll
    for (int h = 0; h < 2; ++h) {
        const int idx = tid * 2 + h;
        float4 M = m_lds[idx], S = s_lds[idx];
        #pragma unroll
        for (int q = 1; q < 4; ++q) {
            float4 pm = m_lds[q * 512 + idx], ps = s_lds[q * 512 + idx];
            float m2;
            m2 = fmaxf(M.x, pm.x); S.x = S.x * exp2f(M.x - m2) + ps.x * exp2f(pm.x - m2); M.x = m2;
            m2 = fmaxf(M.y, pm.y); S.y = S.y * exp2f(M.y - m2) + ps.y * exp2f(pm.y - m2); M.y = m2;
            m2 = fmaxf(M.z, pm.z); S.z = S.z * exp2f(M.z - m2) + ps.z * exp2f(pm.z - m2); M.z = m2;
            m2 = fmaxf(M.w, pm.w); S.w = S.w * exp2f(M.w - m2) + ps.w * exp2f(pm.w - m2); M.w = m2;
        }
        pm_out[idx] = M;
        ps_out[idx] = S;
    }
}

__global__ __launch_bounds__(256)
void comb_kernel(const float* __restrict__ part_m, const float* __restrict__ part_s,
                 float* __restrict__ ws, int t)
{
    float* v2s = ws + WS_V;
    float* err = ws + WS_ERR;
    if (t > 0 && err[t - 1] < 4.0f * THRESH) return;

    const int g = blockIdx.x * 256 + threadIdx.x;
    const int b = g >> 11, c = g & (P - 1);
    const float* pmb = part_m + (size_t)(b * 128) * P + c;
    const float* psb = part_s + (size_t)(b * 128) * P + c;

    const float A = EPS * __logf(1.0f / (float)P + 1e-8f);

    float M = -1e30f;
    #pragma unroll 8
    for (int q = 0; q < 128; ++q) M = fmaxf(M, pmb[(size_t)q * P]);
    float S = 0.0f;
    #pragma unroll 8
    for (int q = 0; q < 128; ++q)
        S = fmaf(psb[(size_t)q * P], exp2f(pmb[(size_t)q * P] - M), S);

    float v_nat = A - UNSCALE * (M + log2f(S));
    v2s[g] = v_nat * SCALE;
}

__global__ __launch_bounds__(256)
void epi_kernel(float* __restrict__ out, const float* __restrict__ ws)
{
    const float* u2s = ws + WS_U;
    const float* v2s = ws + WS_V;
    float* cost = out;
    float* pi   = out + B;
    const float* C = out + B + (size_t)B * P * P;

    const int bid = blockIdx.x, tid = threadIdx.x;
    const int w = tid >> 6, l = tid & 63;
    const int bb = bid >> 7, rc = bid & 127;
    const int row0 = rc * 16;

    const float4* vv = (const float4*)(v2s + bb * P);
    float4 v4[8];
    #pragma unroll
    for (int k = 0; k < 8; ++k) v4[k] = vv[l + 64 * k];

    float lc = 0.0f;
    #pragma unroll
    for (int j = 0; j < 4; ++j) {
        const int r = row0 + w * 4 + j;
        const float u2 = u2s[bb * P + r];
        const float4* Crow = (const float4*)(C  + (size_t)(bb * P + r) * P);
        float4*       Prow = (float4*)      (pi + (size_t)(bb * P + r) * P);
        #pragma unroll
        for (int k = 0; k < 8; ++k) {
            float4 cc = Crow[l + 64 * k];
            float4 p;
            p.x = exp2f(u2 + v4[k].x - SCALE * cc.x);
            p.y = exp2f(u2 + v4[k].y - SCALE * cc.y);
            p.z = exp2f(u2 + v4[k].z - SCALE * cc.z);
            p.w = exp2f(u2 + v4[k].w - SCALE * cc.w);
            lc = fmaf(p.x, cc.x, lc); lc = fmaf(p.y, cc.y, lc);
            lc = fmaf(p.z, cc.z, lc); lc = fmaf(p.w, cc.w, lc);
            Prow[l + 64 * k] = p;
        }
    }
    #pragma unroll
    for (int off = 1; off < 64; off <<= 1) lc += __shfl_xor(lc, off);
    __shared__ float sm[4];
    if (l == 0) sm[w] = lc;
    __syncthreads();
    if (tid == 0) atomicAdd(&cost[bb], sm[0] + sm[1] + sm[2] + sm[3]);
}

extern "C" void kernel_launch(void* const* d_in, const int* in_sizes, int n_in,
                              void* d_out, int out_size, void* d_ws, size_t ws_size,
                              hipStream_t stream) {
    const float* x = (const float*)d_in[0];
    const float* y = (const float*)d_in[1];
    float* out = (float*)d_out;
    float* ws  = (float*)d_ws;
    const float* C = out + B + (size_t)B * P * P;
    // persist partials: [batch][colpair 1024][chunk 64] float4 = 4 MB, in pi region
    float4* part4 = (float4*)(out + B);
    // fallback partials (same region, old layout)
    float* part_m = out + B;
    float* part_s = part_m + 512 * P;

    prep_kernel<<<2048, 256, 0, stream>>>(x, y, out, ws);

    void* args[] = { (void*)&C, (void*)&part4, (void*)&ws, (void*)&out };
    hipError_t e = hipLaunchCooperativeKernel((void*)persist_kernel,
                                              dim3(NBLK), dim3(NTHR),
                                              args, 0, stream);
    if (e != hipSuccess) {
        for (int t = 0; t < MAX_ITER; ++t) {
            iter_kernel<<<512, 256, 0, stream>>>(C, part_m, part_s, ws, t);
            comb_kernel<<<32,  256, 0, stream>>>(part_m, part_s, ws, t);
        }
        epi_kernel<<<512, 256, 0, stream>>>(out, ws);
    }
}